// Round 5
// baseline (602.372 us; speedup 1.0000x reference)
//
#include <hip/hip_runtime.h>
#include <cstdint>
#include <cstddef>

// Problem constants (B=8,T=4,N1=1024,N2=64,D=1024,H=16,DH=64)
constexpr int CB = 8, CT = 4, CN1 = 1024, CN2 = 64, CD = 1024, CH = 16, CDH = 64;
constexpr int CBT = CB * CT;          // 32
constexpr int CNK = CN1 + 1;          // 1025
constexpr int CINNER = CH * CDH;      // 1024

// ---------- bf16 helpers (raw ushort storage) ----------
__device__ __forceinline__ unsigned short f2bf(float f) {
  union { float f; unsigned int u; } v; v.f = f;
  unsigned int u = v.u;
  u += 0x7fffu + ((u >> 16) & 1u);    // RNE
  return (unsigned short)(u >> 16);
}

// ---------- MFMA types ----------
typedef __attribute__((ext_vector_type(8))) short short8;
typedef __attribute__((ext_vector_type(8))) __bf16 bf16x8;
typedef __attribute__((ext_vector_type(4))) float floatx4;

template <typename V>
__device__ __forceinline__ auto mfma_bf16_impl(V a, V b, floatx4 c, int)
    -> decltype(__builtin_amdgcn_mfma_f32_16x16x32_bf16(a, b, c, 0, 0, 0)) {
  return __builtin_amdgcn_mfma_f32_16x16x32_bf16(a, b, c, 0, 0, 0);
}
template <typename V>
__device__ __forceinline__ floatx4 mfma_bf16_impl(V a, V b, floatx4 c, long) {
  return __builtin_amdgcn_mfma_f32_16x16x32_bf16(
      __builtin_bit_cast(bf16x8, a), __builtin_bit_cast(bf16x8, b), c, 0, 0, 0);
}
__device__ __forceinline__ floatx4 mfma_bf16(short8 a, short8 b, floatx4 c) {
  return mfma_bf16_impl(a, b, c, 0);
}

// ---------- async global->LDS (16B/lane), guarded w/ manual fallback ----------
#if __has_builtin(__builtin_amdgcn_global_load_lds)
#define HAS_GLDS 1
__device__ __forceinline__ void glds16(const unsigned short* g, unsigned short* l) {
  __builtin_amdgcn_global_load_lds(
      (const __attribute__((address_space(1))) void*)g,
      (__attribute__((address_space(3))) void*)l, 16, 0, 0);
}
#else
#define HAS_GLDS 0
#endif

// ---------- LayerNorm: one WAVE per row of D=1024; 4 rows/block ----------
__global__ __launch_bounds__(256) void ln_kernel(
    const float* __restrict__ x, const float* __restrict__ g,
    const float* __restrict__ b, unsigned short* __restrict__ obf,
    float* __restrict__ of32) {
  const int row = blockIdx.x * 4 + (threadIdx.x >> 6);
  const int lane = threadIdx.x & 63;
  const float4* xr = (const float4*)(x + (size_t)row * CD);
  float4 v[4];
#pragma unroll
  for (int k = 0; k < 4; ++k) v[k] = xr[lane + 64 * k];
  float s = 0.f, s2 = 0.f;
#pragma unroll
  for (int k = 0; k < 4; ++k) {
    s  += v[k].x + v[k].y + v[k].z + v[k].w;
    s2 += v[k].x*v[k].x + v[k].y*v[k].y + v[k].z*v[k].z + v[k].w*v[k].w;
  }
#pragma unroll
  for (int off = 32; off; off >>= 1) { s += __shfl_xor(s, off); s2 += __shfl_xor(s2, off); }
  const float mean = s * (1.0f / 1024.0f);
  const float var  = s2 * (1.0f / 1024.0f) - mean * mean;   // == jnp.var (ddof=0)
  const float rstd = rsqrtf(var + 1e-5f);
#pragma unroll
  for (int k = 0; k < 4; ++k) {
    const float4 gv = ((const float4*)g)[lane + 64 * k];
    const float4 bv = ((const float4*)b)[lane + 64 * k];
    float4 y;
    y.x = (v[k].x - mean) * rstd * gv.x + bv.x;
    y.y = (v[k].y - mean) * rstd * gv.y + bv.y;
    y.z = (v[k].z - mean) * rstd * gv.z + bv.z;
    y.w = (v[k].w - mean) * rstd * gv.w + bv.w;
    ushort4 o; o.x = f2bf(y.x); o.y = f2bf(y.y); o.z = f2bf(y.z); o.w = f2bf(y.w);
    ((ushort4*)(obf + (size_t)row * CD))[lane + 64 * k] = o;
    if (of32) ((float4*)(of32 + (size_t)row * CD))[lane + 64 * k] = y;
  }
}

// ---------- weight transpose + bf16 convert: W[K][N] f32 -> WT[N][K] bf16 ----
__global__ __launch_bounds__(256) void wtrans_kernel(
    const float* __restrict__ W, unsigned short* __restrict__ WT, int K, int N) {
  __shared__ float t[64][65];
  const int n0 = blockIdx.x * 64, k0 = blockIdx.y * 64;
  const int tid = threadIdx.x;
  const int kr = tid >> 4, ns = (tid & 15) * 4;
#pragma unroll
  for (int i = 0; i < 4; ++i) {
    const int k = kr + i * 16;
    const float4 v = *(const float4*)&W[(size_t)(k0 + k) * N + n0 + ns];
    t[k][ns + 0] = v.x; t[k][ns + 1] = v.y; t[k][ns + 2] = v.z; t[k][ns + 3] = v.w;
  }
  __syncthreads();
  const int n = tid >> 2, ks = (tid & 3) * 16;
#pragma unroll
  for (int c = 0; c < 4; ++c) {
    ushort4 o;
    o.x = f2bf(t[ks + c * 4 + 0][n]);
    o.y = f2bf(t[ks + c * 4 + 1][n]);
    o.z = f2bf(t[ks + c * 4 + 2][n]);
    o.w = f2bf(t[ks + c * 4 + 3][n]);
    *(ushort4*)&WT[(size_t)(n0 + n) * K + k0 + ks + c * 4] = o;
  }
}

// ---------- m97-structure GEMM: C[M,N] = A[M,K] @ BT[N,K]^T (Q/out GEMMs) ----
template <bool A_KV, bool C_BF16>
__global__ __launch_bounds__(256) void gemm128_kernel(
    const unsigned short* __restrict__ A, const unsigned short* __restrict__ xn,
    const unsigned short* __restrict__ lnb, const unsigned short* __restrict__ BT,
    unsigned short* __restrict__ Cb, float* __restrict__ Cf,
    int M, int N, int K) {
  __shared__ __attribute__((aligned(16))) unsigned short As[128 * 32];
  __shared__ __attribute__((aligned(16))) unsigned short Bs[128 * 32];
  const int tid = threadIdx.x;
  const int col0 = blockIdx.x * 128, row0 = blockIdx.y * 128;
  const int srow = tid >> 2, skseg = (tid & 3) * 8;

  auto arow_ptr = [&](int grow) -> const unsigned short* {
    if (grow >= M) grow = M - 1;
    if (A_KV) {
      const int bt = grow / CNK, j = grow - bt * CNK;
      return (j < CN1) ? xn + ((size_t)(bt * CN1 + j)) * K + skseg
                       : lnb + ((size_t)(bt * CN2)) * K + skseg;  // ln[:, :, 0]
    }
    return A + (size_t)grow * K + skseg;
  };
  const unsigned short* a0 = arow_ptr(row0 + srow);
  const unsigned short* a1 = arow_ptr(row0 + 64 + srow);
  const unsigned short* b0 = BT + (size_t)(col0 + srow) * K + skseg;
  const unsigned short* b1 = BT + (size_t)(col0 + 64 + srow) * K + skseg;

  const int lane = tid & 63, wave = tid >> 6;
  const int wrow = (wave >> 1) * 64, wcol = (wave & 1) * 64;
  const int i16 = lane & 15, quad = lane >> 4;

  floatx4 acc[4][4] = {};
  for (int kt = 0; kt < K; kt += 32) {
    __syncthreads();
#if HAS_GLDS
    glds16(a0 + kt, &As[tid * 8]);
    glds16(a1 + kt, &As[2048 + tid * 8]);
    glds16(b0 + kt, &Bs[tid * 8]);
    glds16(b1 + kt, &Bs[2048 + tid * 8]);
#else
    *(uint4*)&As[tid * 8]        = *(const uint4*)(a0 + kt);
    *(uint4*)&As[2048 + tid * 8] = *(const uint4*)(a1 + kt);
    *(uint4*)&Bs[tid * 8]        = *(const uint4*)(b0 + kt);
    *(uint4*)&Bs[2048 + tid * 8] = *(const uint4*)(b1 + kt);
#endif
    __syncthreads();
    short8 af[4], bf[4];
#pragma unroll
    for (int ti = 0; ti < 4; ++ti)
      af[ti] = *(const short8*)&As[(wrow + ti * 16 + i16) * 32 + quad * 8];
#pragma unroll
    for (int tj = 0; tj < 4; ++tj)
      bf[tj] = *(const short8*)&Bs[(wcol + tj * 16 + i16) * 32 + quad * 8];
#pragma unroll
    for (int ti = 0; ti < 4; ++ti)
#pragma unroll
      for (int tj = 0; tj < 4; ++tj)
        acc[ti][tj] = mfma_bf16(af[ti], bf[tj], acc[ti][tj]);
  }
#pragma unroll
  for (int ti = 0; ti < 4; ++ti)
#pragma unroll
    for (int tj = 0; tj < 4; ++tj) {
      const int gc = col0 + wcol + tj * 16 + i16;
#pragma unroll
      for (int r = 0; r < 4; ++r) {
        const int gr = row0 + wrow + ti * 16 + quad * 4 + r;
        if (gr < M) {
          if (C_BF16) Cb[(size_t)gr * N + gc] = f2bf(acc[ti][tj][r]);
          else        Cf[(size_t)gr * N + gc] = acc[ti][tj][r];
        }
      }
    }
}

// ---------- KV GEMM: 256^2 tile, 8 waves, A-only LDS ring, B direct --------
// (resubmission of r4 -- container-level infra failure, no kernel signal)
// Rationale (r3 post-mortem): all prior structures were LDS-traffic-bound
// (~54 B/cyc of 128). B is the 4 MB weight matrix -> read its fragments
// DIRECTLY from global (L2-resident: XCD = blockIdx%8 = nb, so each XCD owns
// one 512 KB B column-panel). Only A goes through the proven 3-slot swizzled
// LDS ring. LDS traffic/CU-slice: 80 KB (~940 cyc) < MFMA 1242 cyc -> the
// matrix pipe is now the binding resource.
// B latency hiding: B(s+1) prefetched into register ping-pong (bfA/bfB)
// during phase s. Counted fences (oldest-first vmcnt semantics):
//   steady fence: allowed-newest = B(s)[4] + stage(s+1)[2] -> vmcnt(6)
//   final phase:  allowed = B(31)[4]                       -> vmcnt(4)
// Prologue issues stage(0),stage(1) BEFORE B(0) so vmcnt(6) provably drains
// stage(0). Slot-reuse proof identical to r3 (lag-2, 3 slots, fence->barrier:
// barrier release => all waves' slice-s stages landed & slice s-1 reads done).
// A swizzle: read slot16 = quad ^ ((row>>1)&3); inverse permutation applied
// to the GLOBAL source address (LDS dest lane-linear for global_load_lds).
template <bool A_KV>
__global__ __launch_bounds__(512, 2) void gemmkv_kernel(
    const unsigned short* __restrict__ xn, const unsigned short* __restrict__ lnb,
    const unsigned short* __restrict__ BT, unsigned short* __restrict__ Cb,
    int M, int N, int K) {
  __shared__ __attribute__((aligned(16))) unsigned short As[3 * 8192];  // 3 x (256x32)
  const int tid = threadIdx.x;
  const int mb = blockIdx.x >> 3, nb = blockIdx.x & 7;   // XCD = blockIdx%8 = nb
  const int row0 = mb * 256, col0 = nb * 256;

  auto arow = [&](int grow) -> const unsigned short* {
    if (grow >= M) grow = M - 1;
    if (A_KV) {
      const int bt = grow / CNK, j = grow - bt * CNK;
      return (j < CN1) ? xn + ((size_t)(bt * CN1 + j)) * K
                       : lnb + ((size_t)(bt * CN2)) * K;   // ln[:, :, 0]
    }
    return (const unsigned short*)nullptr;  // unused
  };
  // staging: slice = 256 rows x 32 shorts (16 KB) = 1024 chunks of 16B;
  // thread t covers chunks t and t+512. dest lane-linear; source pre-swizzled.
  const int c0 = tid, c1 = tid + 512;
  const int rA0 = c0 >> 2, sA0 = (c0 & 3) ^ ((rA0 >> 1) & 3);
  const int rA1 = c1 >> 2, sA1 = (c1 & 3) ^ ((rA1 >> 1) & 3);
  const unsigned short* pA0 = arow(row0 + rA0) + sA0 * 8;
  const unsigned short* pA1 = arow(row0 + rA1) + sA1 * 8;

  auto stage = [&](int s) {
    const int sb = (s % 3) * 8192;
#if HAS_GLDS
    glds16(pA0 + s * 32, &As[sb + tid * 8]);
    glds16(pA1 + s * 32, &As[sb + 4096 + tid * 8]);
#else
    *(uint4*)&As[sb + tid * 8]        = *(const uint4*)(pA0 + s * 32);
    *(uint4*)&As[sb + 4096 + tid * 8] = *(const uint4*)(pA1 + s * 32);
#endif
  };

  const int lane = tid & 63, wave = tid >> 6;
  const int wr = wave >> 2, wc = wave & 3;      // 2M x 4N; per-wave 128x64
  const int i16 = lane & 15, quad = lane >> 4;
  int offA[8];
#pragma unroll
  for (int ti = 0; ti < 8; ++ti) {
    const int r = wr * 128 + ti * 16 + i16;
    offA[ti] = r * 32 + (quad ^ ((r >> 1) & 3)) * 8;
  }
  const unsigned short* pB[4];
#pragma unroll
  for (int tj = 0; tj < 4; ++tj) {
    const int col = col0 + wc * 64 + tj * 16 + i16;
    pB[tj] = BT + (size_t)col * K + quad * 8;
  }

  floatx4 acc[8][4] = {};
  short8 bfA[4], bfB[4];

  // prologue: stages FIRST, then B(0) (vmcnt order: fence vmcnt(6) must
  // drain stage(0) = the oldest 2 VMEM ops).
  stage(0); stage(1);
  __builtin_amdgcn_sched_barrier(0);
#pragma unroll
  for (int tj = 0; tj < 4; ++tj) bfA[tj] = *(const short8*)(pB[tj]);
  __builtin_amdgcn_sched_barrier(0);

  auto phase = [&](int s, short8 (&bfC)[4], short8 (&bfN)[4], bool preB, bool doStage) {
    const unsigned short* Asl = &As[(s % 3) * 8192];
    if (preB) {
#pragma unroll
      for (int tj = 0; tj < 4; ++tj)
        bfN[tj] = *(const short8*)(pB[tj] + (s + 1) * 32);
    }
    __builtin_amdgcn_sched_barrier(0);
    short8 af[8];
#pragma unroll
    for (int ti = 0; ti < 8; ++ti) af[ti] = *(const short8*)(Asl + offA[ti]);
    if (doStage) stage(s + 2);
    __builtin_amdgcn_sched_barrier(0);
    __builtin_amdgcn_s_setprio(1);
#pragma unroll
    for (int ti = 0; ti < 8; ++ti)
#pragma unroll
      for (int tj = 0; tj < 4; ++tj)
        acc[ti][tj] = mfma_bf16(af[ti], bfC[tj], acc[ti][tj]);
    __builtin_amdgcn_s_setprio(0);
  };

  const int NSL = K >> 5;   // 32 slices of K=32
  for (int s = 0; s < NSL; s += 2) {
    asm volatile("s_waitcnt vmcnt(6)" ::: "memory");
    __builtin_amdgcn_s_barrier();
    __builtin_amdgcn_sched_barrier(0);
    phase(s, bfA, bfB, true, s + 2 < NSL);
    if (s + 1 == NSL - 1) { asm volatile("s_waitcnt vmcnt(4)" ::: "memory"); }
    else                  { asm volatile("s_waitcnt vmcnt(6)" ::: "memory"); }
    __builtin_amdgcn_s_barrier();
    __builtin_amdgcn_sched_barrier(0);
    phase(s + 1, bfB, bfA, s + 2 < NSL, s + 3 < NSL);
  }

#pragma unroll
  for (int ti = 0; ti < 8; ++ti)
#pragma unroll
    for (int tj = 0; tj < 4; ++tj) {
      const int gc = col0 + wc * 64 + tj * 16 + i16;
#pragma unroll
      for (int r = 0; r < 4; ++r) {
        const int gr = row0 + wr * 128 + ti * 16 + quad * 4 + r;
        if (gr < M) Cb[(size_t)gr * N + gc] = f2bf(acc[ti][tj][r]);
      }
    }
}

// ---------- dynamic head weights, stage 1: mean over latent rows ----------
__global__ __launch_bounds__(256) void dwmean_kernel(
    const float* __restrict__ lnf, float* __restrict__ meanp) {
  const int bt = blockIdx.x >> 2, dseg = blockIdx.x & 3;
  const int d = dseg * 256 + threadIdx.x;
  const float* base = lnf + (size_t)bt * CN2 * CD + d;
  float s = 0.f;
#pragma unroll 4
  for (int r = 0; r < CN2; ++r) s += base[(size_t)r * CD];
  meanp[bt * CD + d] = s * (1.0f / 64.0f);
}

// ---------- dw stage 2: hid = relu(mean @ Wd1 + bd1) ----------
__global__ __launch_bounds__(256) void dwmlp_kernel(
    const float* __restrict__ meanp, const float* __restrict__ Wd1,
    const float* __restrict__ bd1, float* __restrict__ hidp) {
  __shared__ float red[8][32];
  const int bt = blockIdx.x >> 3, og = blockIdx.x & 7;
  const int o = threadIdx.x & 31, seg = threadIdx.x >> 5;
  const int col = og * 32 + o;
  const float* mb = meanp + bt * CD;
  float s = 0.f;
#pragma unroll 4
  for (int d = seg * 128; d < seg * 128 + 128; ++d)
    s += mb[d] * Wd1[(size_t)d * 256 + col];
  red[seg][o] = s;
  __syncthreads();
  if (seg == 0) {
    float t = red[0][o];
#pragma unroll
    for (int k = 1; k < 8; ++k) t += red[k][o];
    hidp[bt * 256 + col] = fmaxf(t + bd1[col], 0.0f);
  }
}

// ---------- dw stage 3: dw = softmax(hid @ Wd2 + bd2) ----------
__global__ __launch_bounds__(256) void dwfin_kernel(
    const float* __restrict__ hidp, const float* __restrict__ Wd2,
    const float* __restrict__ bd2, float* __restrict__ dw) {
  __shared__ float red[16][16];
  __shared__ float lg[16];
  const int bt = blockIdx.x;
  const int h = threadIdx.x & 15, seg = threadIdx.x >> 4;
  const float* hb = hidp + bt * 256;
  float s = 0.f;
#pragma unroll
  for (int o = seg * 16; o < seg * 16 + 16; ++o)
    s += hb[o] * Wd2[o * 16 + h];
  red[seg][h] = s;
  __syncthreads();
  if (seg == 0) {
    float t = red[0][h];
#pragma unroll
    for (int k = 1; k < 16; ++k) t += red[k][h];
    lg[h] = t + bd2[h];
  }
  __syncthreads();
  if (threadIdx.x < 16) {
    float mx = lg[0];
#pragma unroll
    for (int k = 1; k < 16; ++k) mx = fmaxf(mx, lg[k]);
    float sum = 0.f;
#pragma unroll
    for (int k = 0; k < 16; ++k) sum += __expf(lg[k] - mx);
    dw[bt * 16 + threadIdx.x] = __expf(lg[threadIdx.x] - mx) / sum;
  }
}

// ---------- MFMA attention v2: block per (b,t,h), 4 waves x 16 q-rows ----------
__global__ __launch_bounds__(256) void attn_kernel(
    const unsigned short* __restrict__ Q,   // (BT*64) x 1024, col = h*64+d
    const unsigned short* __restrict__ KV,  // (BT*1025) x 2048, K then V
    const float* __restrict__ dw,           // BT x 16
    unsigned short* __restrict__ AO) {      // (BT*64) x 1024, col = h*64+d
  __shared__ __attribute__((aligned(16))) unsigned short ks[2][64 * 72];  // K: [key][d]
  __shared__ __attribute__((aligned(16))) unsigned short vt[2][64 * 72];  // V^T: [d][perm key]
  const int raw = blockIdx.x;
  const int bt = (raw & 7) * 4 + ((raw >> 3) >> 4);
  const int h  = (raw >> 3) & 15;
  const int tid = threadIdx.x;
  const int lane = tid & 63, wave = tid >> 6;
  const int i16 = lane & 15, quad = lane >> 4;
  const int wrow = wave * 16;

  const unsigned short* qbase =
      Q + ((size_t)(bt * 64 + wrow + i16)) * CINNER + h * 64;
  const short8 bq0 = *(const short8*)(qbase + quad * 8);        // d 0..31
  const short8 bq1 = *(const short8*)(qbase + 32 + quad * 8);   // d 32..63

  const int jrb = tid & 31, seg = tid >> 5;
  const int t_ = jrb & 15, hlf_ = jrb >> 4;
  const int vcol0 = ((t_ >> 2) << 3) + (t_ & 3) + 4 * hlf_;  // + c*32
  const unsigned short* kvb = KV + ((size_t)bt * CNK) * 2048 + h * 64 + seg * 8;

  uint4 kk[2], vv[2];
  auto load_tile = [&](int j0) {
#pragma unroll
    for (int c = 0; c < 2; ++c) {
      const int j = j0 + c * 32 + jrb;
      if (j < CNK) {
        const unsigned short* p = kvb + (size_t)j * 2048;
        kk[c] = *(const uint4*)p;
        vv[c] = *(const uint4*)(p + 1024);
      } else {
        kk[c] = make_uint4(0, 0, 0, 0);
        vv[c] = make_uint4(0, 0, 0, 0);
      }
    }
  };
  auto write_tile = [&](int buf) {
#pragma unroll
    for (int c = 0; c < 2; ++c) {
      const int jr = c * 32 + jrb;
      *(uint4*)&ks[buf][jr * 72 + seg * 8] = kk[c];
      const int vcol = c * 32 + vcol0;
      const unsigned int w[4] = {vv[c].x, vv[c].y, vv[c].z, vv[c].w};
#pragma unroll
      for (int p = 0; p < 4; ++p) {
        vt[buf][(seg * 8 + 2 * p + 0) * 72 + vcol] = (unsigned short)(w[p] & 0xffffu);
        vt[buf][(seg * 8 + 2 * p + 1) * 72 + vcol] = (unsigned short)(w[p] >> 16);
      }
    }
  };

  float l = 0.f;
  floatx4 O[4] = {{0,0,0,0}, {0,0,0,0}, {0,0,0,0}, {0,0,0,0}};
  const float expC = 0.18033688011112042f;  // 0.125 * log2(e)

  load_tile(0);
  write_tile(0);
  constexpr int NT = 17;  // ceil(1025/64)
  for (int t = 0; t < NT; ++t) {
    if (t + 1 < NT) load_tile((t + 1) * 64);
    __syncthreads();
    const int buf = t & 1;
    const unsigned short* ksb = ks[buf];
    const unsigned short* vtb = vt[buf];
#pragma unroll
    for (int c = 0; c < 2; ++c) {
      floatx4 s0 = {0,0,0,0}, s1 = {0,0,0,0};
      const short8 a00 = *(const short8*)&ksb[((2*c)   * 16 + i16) * 72 + quad * 8];
      const short8 a01 = *(const short8*)&ksb[((2*c)   * 16 + i16) * 72 + 32 + quad * 8];
      const short8 a10 = *(const short8*)&ksb[((2*c+1) * 16 + i16) * 72 + quad * 8];
      const short8 a11 = *(const short8*)&ksb[((2*c+1) * 16 + i16) * 72 + 32 + quad * 8];
      s0 = mfma_bf16(a00, bq0, s0); s0 = mfma_bf16(a01, bq1, s0);
      s1 = mfma_bf16(a10, bq0, s1); s1 = mfma_bf16(a11, bq1, s1);
      unsigned short pb0[4], pb1[4];
      if (t == NT - 1) {  // masked tail tile (keys 1024..1087; only 1024 valid)
#pragma unroll
        for (int r = 0; r < 4; ++r) {
          const int k0g = t * 64 + (2*c)   * 16 + quad * 4 + r;
          const int k1g = t * 64 + (2*c+1) * 16 + quad * 4 + r;
          const float p0 = (k0g < CNK) ? exp2f(s0[r] * expC) : 0.f;
          const float p1 = (k1g < CNK) ? exp2f(s1[r] * expC) : 0.f;
          l += p0 + p1;
          pb0[r] = f2bf(p0); pb1[r] = f2bf(p1);
        }
      } else {
#pragma unroll
        for (int r = 0; r < 4; ++r) {
          const float p0 = exp2f(s0[r] * expC);
          const float p1 = exp2f(s1[r] * expC);
          l += p0 + p1;
          pb0[r] = f2bf(p0); pb1[r] = f2bf(p1);
        }
      }
      const short8 bp = {
          (short)pb0[0], (short)pb0[1], (short)pb0[2], (short)pb0[3],
          (short)pb1[0], (short)pb1[1], (short)pb1[2], (short)pb1[3]};
#pragma unroll
      for (int dt = 0; dt < 4; ++dt) {
        const short8 av = *(const short8*)&vtb[(dt * 16 + i16) * 72 + c * 32 + quad * 8];
        O[dt] = mfma_bf16(av, bp, O[dt]);
      }
    }
    if (t + 1 < NT) write_tile((t + 1) & 1);
  }

  l += __shfl_xor(l, 16);
  l += __shfl_xor(l, 32);
  const float wsc = dw[bt * 16 + h] / l;
  unsigned short* obase = AO + ((size_t)(bt * 64 + wrow + i16)) * CINNER + h * 64;
#pragma unroll
  for (int dt = 0; dt < 4; ++dt)
#pragma unroll
    for (int r = 0; r < 4; ++r)
      obase[dt * 16 + quad * 4 + r] = f2bf(O[dt][r] * wsc);
}

// ---------- host ----------
extern "C" void kernel_launch(void* const* d_in, const int* in_sizes, int n_in,
                              void* d_out, int out_size, void* d_ws, size_t ws_size,
                              hipStream_t stream) {
  const float* x       = (const float*)d_in[0];
  const float* latents = (const float*)d_in[1];
  const float* gm  = (const float*)d_in[2];
  const float* bm  = (const float*)d_in[3];
  const float* gl  = (const float*)d_in[4];
  const float* bl  = (const float*)d_in[5];
  const float* Wq  = (const float*)d_in[6];
  const float* Wkv = (const float*)d_in[7];
  const float* Wout= (const float*)d_in[8];
  const float* Wd1 = (const float*)d_in[9];
  const float* bd1 = (const float*)d_in[10];
  const float* Wd2 = (const float*)d_in[11];
  const float* bd2 = (const float*)d_in[12];
  float* out = (float*)d_out;

  char* ws = (char*)d_ws;
  size_t off = 0;
  auto alloc = [&](size_t bytes) -> void* {
    void* p = ws + off;
    off += (bytes + 255) & ~(size_t)255;
    return p;
  };
  unsigned short* xn   = (unsigned short*)alloc((size_t)CBT * CN1 * CD * 2);      // 64 MB
  unsigned short* kv   = (unsigned short*)alloc((size_t)CBT * CNK * 2048 * 2);    // 131 MB
  float*          lnf  = (float*)        alloc((size_t)CBT * CN2 * CD * 4);       // 8 MB
  unsigned short* lnb  = (unsigned short*)alloc((size_t)CBT * CN2 * CD * 2);      // 4 MB
  unsigned short* wqT  = (unsigned short*)alloc((size_t)CD * CINNER * 2);         // 2 MB  [N][K]
  unsigned short* wkvT = (unsigned short*)alloc((size_t)CD * 2 * CINNER * 2);     // 4 MB  [2N][K]
  unsigned short* woT  = (unsigned short*)alloc((size_t)CINNER * CD * 2);         // 2 MB  [N][K]
  unsigned short* qb   = (unsigned short*)alloc((size_t)CBT * CN2 * CINNER * 2);  // 4 MB
  unsigned short* aob  = (unsigned short*)alloc((size_t)CBT * CN2 * CINNER * 2);  // 4 MB
  float*          dwp  = (float*)        alloc((size_t)CBT * CH * 4);
  float*          meanp= (float*)        alloc((size_t)CBT * CD * 4);             // 128 KB
  float*          hidp = (float*)        alloc((size_t)CBT * 256 * 4);            // 32 KB
  if (off > ws_size) return;  // signal: output stays zero (ws too small)

  // 1) layernorms (x -> bf16; latents -> bf16 + fp32)
  ln_kernel<<<CBT * CN1 / 4, 256, 0, stream>>>(x, gm, bm, xn, nullptr);
  ln_kernel<<<CBT * CN2 / 4, 256, 0, stream>>>(latents, gl, bl, lnb, lnf);
  // 2) weight transpose + bf16 convert: W[K][N] -> WT[N][K]
  wtrans_kernel<<<dim3(CINNER / 64, CD / 64), 256, 0, stream>>>(Wq, wqT, CD, CINNER);
  wtrans_kernel<<<dim3(2 * CINNER / 64, CD / 64), 256, 0, stream>>>(Wkv, wkvT, CD, 2 * CINNER);
  wtrans_kernel<<<dim3(CD / 64, CINNER / 64), 256, 0, stream>>>(Wout, woT, CINNER, CD);
  // 3) Q = ln @ Wq   (2048 x 1024 x 1024)
  gemm128_kernel<false, true><<<dim3(1024 / 128, 2048 / 128), 256, 0, stream>>>(
      lnb, nullptr, nullptr, wqT, qb, nullptr, 2048, 1024, 1024);
  // 4) KV = concat(xn, ln[:, :, 0:1]) @ Wkv   (32800 x 2048 x 1024)
  //    256^2 tile, 8 waves, A-only LDS ring + B-direct-from-L2.
  //    grid = ceil(M/256) x 8 col-panels; blockIdx%8 = col-panel = XCD.
  {
    const int MB = (CBT * CNK + 255) / 256;   // 129
    gemmkv_kernel<true><<<MB * 8, 512, 0, stream>>>(
        xn, lnb, wkvT, kv, CBT * CNK, 2048, 1024);
  }
  // 5) dynamic head weights (3-stage, parallel)
  dwmean_kernel<<<CBT * 4, 256, 0, stream>>>(lnf, meanp);
  dwmlp_kernel<<<CBT * 8, 256, 0, stream>>>(meanp, Wd1, bd1, hidp);
  dwfin_kernel<<<CBT, 256, 0, stream>>>(hidp, Wd2, bd2, dwp);
  // 6) attention (512 blocks = BT * H, XCD-grouped by bt)
  attn_kernel<<<CBT * CH, 256, 0, stream>>>(qb, kv, dwp, aob);
  // 7) out = AO @ Wout   (2048 x 1024 x 1024) -> fp32 d_out
  gemm128_kernel<false, false><<<dim3(1024 / 128, 2048 / 128), 256, 0, stream>>>(
      aob, nullptr, nullptr, woT, nullptr, out, 2048, 1024, 1024);
}

// Round 6
// 550.620 us; speedup vs baseline: 1.0940x; 1.0940x over previous
//
#include <hip/hip_runtime.h>
#include <cstdint>
#include <cstddef>

// Problem constants (B=8,T=4,N1=1024,N2=64,D=1024,H=16,DH=64)
constexpr int CB = 8, CT = 4, CN1 = 1024, CN2 = 64, CD = 1024, CH = 16, CDH = 64;
constexpr int CBT = CB * CT;          // 32
constexpr int CNK = CN1 + 1;          // 1025
constexpr int CINNER = CH * CDH;      // 1024

// ---------- bf16 helpers (raw ushort storage) ----------
__device__ __forceinline__ unsigned short f2bf(float f) {
  union { float f; unsigned int u; } v; v.f = f;
  unsigned int u = v.u;
  u += 0x7fffu + ((u >> 16) & 1u);    // RNE
  return (unsigned short)(u >> 16);
}

// ---------- MFMA types ----------
typedef __attribute__((ext_vector_type(8))) short short8;
typedef __attribute__((ext_vector_type(8))) __bf16 bf16x8;
typedef __attribute__((ext_vector_type(4))) float floatx4;

template <typename V>
__device__ __forceinline__ auto mfma_bf16_impl(V a, V b, floatx4 c, int)
    -> decltype(__builtin_amdgcn_mfma_f32_16x16x32_bf16(a, b, c, 0, 0, 0)) {
  return __builtin_amdgcn_mfma_f32_16x16x32_bf16(a, b, c, 0, 0, 0);
}
template <typename V>
__device__ __forceinline__ floatx4 mfma_bf16_impl(V a, V b, floatx4 c, long) {
  return __builtin_amdgcn_mfma_f32_16x16x32_bf16(
      __builtin_bit_cast(bf16x8, a), __builtin_bit_cast(bf16x8, b), c, 0, 0, 0);
}
__device__ __forceinline__ floatx4 mfma_bf16(short8 a, short8 b, floatx4 c) {
  return mfma_bf16_impl(a, b, c, 0);
}

// ---------- async global->LDS (16B/lane), guarded w/ manual fallback ----------
#if __has_builtin(__builtin_amdgcn_global_load_lds)
#define HAS_GLDS 1
__device__ __forceinline__ void glds16(const unsigned short* g, unsigned short* l) {
  __builtin_amdgcn_global_load_lds(
      (const __attribute__((address_space(1))) void*)g,
      (__attribute__((address_space(3))) void*)l, 16, 0, 0);
}
#else
#define HAS_GLDS 0
#endif

#define FENCEV(n) asm volatile("s_waitcnt vmcnt(" #n ")" ::: "memory")
#define SBAR __builtin_amdgcn_s_barrier()
#define LGKM0 do { asm volatile("s_waitcnt lgkmcnt(0)" ::: "memory"); \
                   __builtin_amdgcn_sched_barrier(0); } while (0)

// ---------- LayerNorm: one WAVE per row of D=1024; 4 rows/block ----------
__global__ __launch_bounds__(256) void ln_kernel(
    const float* __restrict__ x, const float* __restrict__ g,
    const float* __restrict__ b, unsigned short* __restrict__ obf,
    float* __restrict__ of32) {
  const int row = blockIdx.x * 4 + (threadIdx.x >> 6);
  const int lane = threadIdx.x & 63;
  const float4* xr = (const float4*)(x + (size_t)row * CD);
  float4 v[4];
#pragma unroll
  for (int k = 0; k < 4; ++k) v[k] = xr[lane + 64 * k];
  float s = 0.f, s2 = 0.f;
#pragma unroll
  for (int k = 0; k < 4; ++k) {
    s  += v[k].x + v[k].y + v[k].z + v[k].w;
    s2 += v[k].x*v[k].x + v[k].y*v[k].y + v[k].z*v[k].z + v[k].w*v[k].w;
  }
#pragma unroll
  for (int off = 32; off; off >>= 1) { s += __shfl_xor(s, off); s2 += __shfl_xor(s2, off); }
  const float mean = s * (1.0f / 1024.0f);
  const float var  = s2 * (1.0f / 1024.0f) - mean * mean;   // == jnp.var (ddof=0)
  const float rstd = rsqrtf(var + 1e-5f);
#pragma unroll
  for (int k = 0; k < 4; ++k) {
    const float4 gv = ((const float4*)g)[lane + 64 * k];
    const float4 bv = ((const float4*)b)[lane + 64 * k];
    float4 y;
    y.x = (v[k].x - mean) * rstd * gv.x + bv.x;
    y.y = (v[k].y - mean) * rstd * gv.y + bv.y;
    y.z = (v[k].z - mean) * rstd * gv.z + bv.z;
    y.w = (v[k].w - mean) * rstd * gv.w + bv.w;
    ushort4 o; o.x = f2bf(y.x); o.y = f2bf(y.y); o.z = f2bf(y.z); o.w = f2bf(y.w);
    ((ushort4*)(obf + (size_t)row * CD))[lane + 64 * k] = o;
    if (of32) ((float4*)(of32 + (size_t)row * CD))[lane + 64 * k] = y;
  }
}

// ---------- weight transpose + bf16 convert: W[K][N] f32 -> WT[N][K] bf16 ----
__global__ __launch_bounds__(256) void wtrans_kernel(
    const float* __restrict__ W, unsigned short* __restrict__ WT, int K, int N) {
  __shared__ float t[64][65];
  const int n0 = blockIdx.x * 64, k0 = blockIdx.y * 64;
  const int tid = threadIdx.x;
  const int kr = tid >> 4, ns = (tid & 15) * 4;
#pragma unroll
  for (int i = 0; i < 4; ++i) {
    const int k = kr + i * 16;
    const float4 v = *(const float4*)&W[(size_t)(k0 + k) * N + n0 + ns];
    t[k][ns + 0] = v.x; t[k][ns + 1] = v.y; t[k][ns + 2] = v.z; t[k][ns + 3] = v.w;
  }
  __syncthreads();
  const int n = tid >> 2, ks = (tid & 3) * 16;
#pragma unroll
  for (int c = 0; c < 4; ++c) {
    ushort4 o;
    o.x = f2bf(t[ks + c * 4 + 0][n]);
    o.y = f2bf(t[ks + c * 4 + 1][n]);
    o.z = f2bf(t[ks + c * 4 + 2][n]);
    o.w = f2bf(t[ks + c * 4 + 3][n]);
    *(ushort4*)&WT[(size_t)(n0 + n) * K + k0 + ks + c * 4] = o;
  }
}

// ---------- m97-structure GEMM: C[M,N] = A[M,K] @ BT[N,K]^T (Q/out GEMMs) ----
template <bool A_KV, bool C_BF16>
__global__ __launch_bounds__(256) void gemm128_kernel(
    const unsigned short* __restrict__ A, const unsigned short* __restrict__ xn,
    const unsigned short* __restrict__ lnb, const unsigned short* __restrict__ BT,
    unsigned short* __restrict__ Cb, float* __restrict__ Cf,
    int M, int N, int K) {
  __shared__ __attribute__((aligned(16))) unsigned short As[128 * 32];
  __shared__ __attribute__((aligned(16))) unsigned short Bs[128 * 32];
  const int tid = threadIdx.x;
  const int col0 = blockIdx.x * 128, row0 = blockIdx.y * 128;
  const int srow = tid >> 2, skseg = (tid & 3) * 8;

  auto arow_ptr = [&](int grow) -> const unsigned short* {
    if (grow >= M) grow = M - 1;
    if (A_KV) {
      const int bt = grow / CNK, j = grow - bt * CNK;
      return (j < CN1) ? xn + ((size_t)(bt * CN1 + j)) * K + skseg
                       : lnb + ((size_t)(bt * CN2)) * K + skseg;  // ln[:, :, 0]
    }
    return A + (size_t)grow * K + skseg;
  };
  const unsigned short* a0 = arow_ptr(row0 + srow);
  const unsigned short* a1 = arow_ptr(row0 + 64 + srow);
  const unsigned short* b0 = BT + (size_t)(col0 + srow) * K + skseg;
  const unsigned short* b1 = BT + (size_t)(col0 + 64 + srow) * K + skseg;

  const int lane = tid & 63, wave = tid >> 6;
  const int wrow = (wave >> 1) * 64, wcol = (wave & 1) * 64;
  const int i16 = lane & 15, quad = lane >> 4;

  floatx4 acc[4][4] = {};
  for (int kt = 0; kt < K; kt += 32) {
    __syncthreads();
#if HAS_GLDS
    glds16(a0 + kt, &As[tid * 8]);
    glds16(a1 + kt, &As[2048 + tid * 8]);
    glds16(b0 + kt, &Bs[tid * 8]);
    glds16(b1 + kt, &Bs[2048 + tid * 8]);
#else
    *(uint4*)&As[tid * 8]        = *(const uint4*)(a0 + kt);
    *(uint4*)&As[2048 + tid * 8] = *(const uint4*)(a1 + kt);
    *(uint4*)&Bs[tid * 8]        = *(const uint4*)(b0 + kt);
    *(uint4*)&Bs[2048 + tid * 8] = *(const uint4*)(b1 + kt);
#endif
    __syncthreads();
    short8 af[4], bf[4];
#pragma unroll
    for (int ti = 0; ti < 4; ++ti)
      af[ti] = *(const short8*)&As[(wrow + ti * 16 + i16) * 32 + quad * 8];
#pragma unroll
    for (int tj = 0; tj < 4; ++tj)
      bf[tj] = *(const short8*)&Bs[(wcol + tj * 16 + i16) * 32 + quad * 8];
#pragma unroll
    for (int ti = 0; ti < 4; ++ti)
#pragma unroll
      for (int tj = 0; tj < 4; ++tj)
        acc[ti][tj] = mfma_bf16(af[ti], bf[tj], acc[ti][tj]);
  }
#pragma unroll
  for (int ti = 0; ti < 4; ++ti)
#pragma unroll
    for (int tj = 0; tj < 4; ++tj) {
      const int gc = col0 + wcol + tj * 16 + i16;
#pragma unroll
      for (int r = 0; r < 4; ++r) {
        const int gr = row0 + wrow + ti * 16 + quad * 4 + r;
        if (gr < M) {
          if (C_BF16) Cb[(size_t)gr * N + gc] = f2bf(acc[ti][tj][r]);
          else        Cf[(size_t)gr * N + gc] = acc[ti][tj][r];
        }
      }
    }
}

// ---------- KV GEMM: 256^2 tile, 8 waves, 8-PHASE schedule (m201 port) ------
// 2 K-tiles (BK=64 each) per iteration, 8 phases. Per phase:
//   {<=12 ds_read_b128 || stage one 16KB half-tile (2 glds)} ; BAR ;
//   lgkmcnt(0)+sched_barrier ; setprio(1) ; 16 MFMA ; setprio(0) ; BAR
// Fragment reuse (quadrant order) keeps reads minimal: per wave per K-tile
// A read at ph1(m0-3)/ph3(m4-7), B at ph1(n0-1)/ph2(n2-3) -> 24 reads.
// Staging wraps iterations: ph1,2 stage tile t+1 tails; ph3-6 tile t+2;
// ph7,8 tile t+3 heads. Each stage is issued after the closing barrier of
// the last phase that READS its destination region (double-barrier lockstep
// discharges every WAR hazard -- verified region-by-region).
// Counted vmcnt, never 0 in steady state: vmcnt(4) before BAR_b of ph4 and
// ph8 (allows exactly the 2 newest half-tile stages in flight; guarantees
// the next tile's 4 half-tiles landed). Prologue: 6 half-tiles + vmcnt(4).
// Last iteration peeled: no ph3-8 stages, vmcnt(0) at ph4.
// Swizzle (both-sides): LDS row = 64 shorts = 8 slots of 16B; read slot =
// (ks*4+quad) ^ (row&7); staging keeps LDS dest lane-linear (glds) and
// applies the same involution to the GLOBAL source slot.
template <bool A_KV>
__global__ __launch_bounds__(512, 2) void gemm8p_kernel(
    const unsigned short* __restrict__ xn, const unsigned short* __restrict__ lnb,
    const unsigned short* __restrict__ BT, unsigned short* __restrict__ Cb,
    int M, int N, int K) {
  __shared__ __attribute__((aligned(16))) unsigned short As[2][2][128 * 64];
  __shared__ __attribute__((aligned(16))) unsigned short Bs[2][2][128 * 64];
  const int tid = threadIdx.x;
  const int mb = blockIdx.x >> 3, nb = blockIdx.x & 7;   // XCD = blockIdx%8 = col panel
  const int row0 = mb * 256, col0 = nb * 256;

  auto arow = [&](int grow) -> const unsigned short* {
    if (grow >= M) grow = M - 1;
    if (A_KV) {
      const int bt = grow / CNK, j = grow - bt * CNK;
      return (j < CN1) ? xn + ((size_t)(bt * CN1 + j)) * K
                       : lnb + ((size_t)(bt * CN2)) * K;   // ln[:, :, 0]
    }
    return (const unsigned short*)nullptr;  // unused
  };

  // staging sources: thread t covers chunks t and t+512 of each 16KB half
  // (128 rows x 64 shorts). chunk c -> row c>>3, dest slot c&7; source slot
  // = (c&7) ^ (row&7). Same source-slot for both chunks (row diff = 64).
  const int rr0 = tid >> 3;                 // 0..63
  const int sl  = (tid & 7) ^ (rr0 & 7);
  const unsigned short* pA[2][2];
  const unsigned short* pB[2][2];
#pragma unroll
  for (int h = 0; h < 2; ++h)
#pragma unroll
    for (int c = 0; c < 2; ++c) {
      pA[h][c] = arow(row0 + h * 128 + rr0 + c * 64) + sl * 8;
      pB[h][c] = BT + (size_t)(col0 + h * 128 + rr0 + c * 64) * K + sl * 8;
    }

  auto stageA = [&](int buf, int h, int t) {
    unsigned short* d = &As[buf][h][tid * 8];
#if HAS_GLDS
    glds16(pA[h][0] + t * 64, d);
    glds16(pA[h][1] + t * 64, d + 4096);
#else
    *(uint4*)d          = *(const uint4*)(pA[h][0] + t * 64);
    *(uint4*)(d + 4096) = *(const uint4*)(pA[h][1] + t * 64);
#endif
  };
  auto stageB = [&](int buf, int h, int t) {
    unsigned short* d = &Bs[buf][h][tid * 8];
#if HAS_GLDS
    glds16(pB[h][0] + t * 64, d);
    glds16(pB[h][1] + t * 64, d + 4096);
#else
    *(uint4*)d          = *(const uint4*)(pB[h][0] + t * 64);
    *(uint4*)(d + 4096) = *(const uint4*)(pB[h][1] + t * 64);
#endif
  };

  const int lane = tid & 63, wave = tid >> 6;
  const int wr = wave >> 2, wc = wave & 3;      // 2M x 4N; per-wave 128x64
  const int i16 = lane & 15, quad = lane >> 4;
  const int sw = i16 & 7;
  const int slk0 = (quad ^ sw) * 8;             // ks=0: slot (0*4+quad)^sw
  const int slk1 = ((4 + quad) ^ sw) * 8;       // ks=1: slot (4+quad)^sw
  const int brow = (wc & 1) * 64;

  short8 aA[8], bB[8];
  floatx4 acc[8][4] = {};

  auto readA4 = [&](const unsigned short* Ah, int mlo) {
#pragma unroll
    for (int i = 0; i < 4; ++i) {
      const int base = ((mlo + i) * 16 + i16) * 64;
      aA[i * 2 + 0] = *(const short8*)(Ah + base + slk0);
      aA[i * 2 + 1] = *(const short8*)(Ah + base + slk1);
    }
  };
  auto readB2 = [&](const unsigned short* Bh, int nlo) {
#pragma unroll
    for (int j = 0; j < 2; ++j) {
      const int base = (brow + (nlo + j) * 16 + i16) * 64;
      bB[(nlo + j) * 2 + 0] = *(const short8*)(Bh + base + slk0);
      bB[(nlo + j) * 2 + 1] = *(const short8*)(Bh + base + slk1);
    }
  };
  auto mfmaQ = [&](int mlo, int nlo) {
    __builtin_amdgcn_s_setprio(1);
#pragma unroll
    for (int i = 0; i < 4; ++i)
#pragma unroll
      for (int j = 0; j < 2; ++j) {
        acc[mlo + i][nlo + j] =
            mfma_bf16(aA[i * 2 + 0], bB[(nlo + j) * 2 + 0], acc[mlo + i][nlo + j]);
        acc[mlo + i][nlo + j] =
            mfma_bf16(aA[i * 2 + 1], bB[(nlo + j) * 2 + 1], acc[mlo + i][nlo + j]);
      }
    __builtin_amdgcn_s_setprio(0);
  };

  // prologue: tile0 all 4 halves + tile1 heads; vmcnt(4) keeps the 2 newest
  // half-tiles (tile1 heads) in flight, drains tile0.
  stageB(0, 0, 0); stageA(0, 0, 0); stageB(0, 1, 0); stageA(0, 1, 0);
  stageB(1, 0, 1); stageA(1, 0, 1);
  FENCEV(4);
  SBAR;

  const unsigned short* A0 = &As[0][wr][0];
  const unsigned short* B0 = &Bs[0][wc >> 1][0];
  const unsigned short* A1 = &As[1][wr][0];
  const unsigned short* B1 = &Bs[1][wc >> 1][0];

  auto iter = [&](int t, bool full) {
    // ---- tile t (buffer 0) ----
    // ph1: Q(m0-3, n0-1)
    readB2(B0, 0); readA4(A0, 0);
    stageB(1, 1, t + 1);
    SBAR; LGKM0;
    mfmaQ(0, 0);
    SBAR;
    // ph2: Q(m0-3, n2-3)
    readB2(B0, 2);
    stageA(1, 1, t + 1);
    SBAR; LGKM0;
    mfmaQ(0, 2);
    SBAR;
    // ph3: Q(m4-7, n0-1)
    readA4(A0, 4);
    if (full) stageB(0, 0, t + 2);
    SBAR; LGKM0;
    mfmaQ(4, 0);
    SBAR;
    // ph4: Q(m4-7, n2-3) -- no reads
    if (full) stageA(0, 0, t + 2);
    SBAR;
    mfmaQ(4, 2);
    if (full) { FENCEV(4); } else { FENCEV(0); }
    SBAR;
    // ---- tile t+1 (buffer 1) ----
    // ph5
    readB2(B1, 0); readA4(A1, 0);
    if (full) stageB(0, 1, t + 2);
    SBAR; LGKM0;
    mfmaQ(0, 0);
    SBAR;
    // ph6
    readB2(B1, 2);
    if (full) stageA(0, 1, t + 2);
    SBAR; LGKM0;
    mfmaQ(0, 2);
    SBAR;
    // ph7
    readA4(A1, 4);
    if (full) stageB(1, 0, t + 3);
    SBAR; LGKM0;
    mfmaQ(4, 0);
    SBAR;
    // ph8 -- no reads
    if (full) stageA(1, 0, t + 3);
    SBAR;
    mfmaQ(4, 2);
    if (full) FENCEV(4);
    SBAR;
  };

  const int NT = K >> 6;                  // 16 K-tiles of 64
  for (int t = 0; t + 2 < NT; t += 2) iter(t, true);
  iter(NT - 2, false);

#pragma unroll
  for (int m = 0; m < 8; ++m)
#pragma unroll
    for (int n = 0; n < 4; ++n) {
      const int gc = col0 + wc * 64 + n * 16 + i16;
#pragma unroll
      for (int r = 0; r < 4; ++r) {
        const int gr = row0 + wr * 128 + m * 16 + quad * 4 + r;
        if (gr < M) Cb[(size_t)gr * N + gc] = f2bf(acc[m][n][r]);
      }
    }
}

// ---------- dynamic head weights, stage 1: mean over latent rows ----------
__global__ __launch_bounds__(256) void dwmean_kernel(
    const float* __restrict__ lnf, float* __restrict__ meanp) {
  const int bt = blockIdx.x >> 2, dseg = blockIdx.x & 3;
  const int d = dseg * 256 + threadIdx.x;
  const float* base = lnf + (size_t)bt * CN2 * CD + d;
  float s = 0.f;
#pragma unroll 4
  for (int r = 0; r < CN2; ++r) s += base[(size_t)r * CD];
  meanp[bt * CD + d] = s * (1.0f / 64.0f);
}

// ---------- dw stage 2: hid = relu(mean @ Wd1 + bd1) ----------
__global__ __launch_bounds__(256) void dwmlp_kernel(
    const float* __restrict__ meanp, const float* __restrict__ Wd1,
    const float* __restrict__ bd1, float* __restrict__ hidp) {
  __shared__ float red[8][32];
  const int bt = blockIdx.x >> 3, og = blockIdx.x & 7;
  const int o = threadIdx.x & 31, seg = threadIdx.x >> 5;
  const int col = og * 32 + o;
  const float* mb = meanp + bt * CD;
  float s = 0.f;
#pragma unroll 4
  for (int d = seg * 128; d < seg * 128 + 128; ++d)
    s += mb[d] * Wd1[(size_t)d * 256 + col];
  red[seg][o] = s;
  __syncthreads();
  if (seg == 0) {
    float t = red[0][o];
#pragma unroll
    for (int k = 1; k < 8; ++k) t += red[k][o];
    hidp[bt * 256 + col] = fmaxf(t + bd1[col], 0.0f);
  }
}

// ---------- dw stage 3: dw = softmax(hid @ Wd2 + bd2) ----------
__global__ __launch_bounds__(256) void dwfin_kernel(
    const float* __restrict__ hidp, const float* __restrict__ Wd2,
    const float* __restrict__ bd2, float* __restrict__ dw) {
  __shared__ float red[16][16];
  __shared__ float lg[16];
  const int bt = blockIdx.x;
  const int h = threadIdx.x & 15, seg = threadIdx.x >> 4;
  const float* hb = hidp + bt * 256;
  float s = 0.f;
#pragma unroll
  for (int o = seg * 16; o < seg * 16 + 16; ++o)
    s += hb[o] * Wd2[o * 16 + h];
  red[seg][h] = s;
  __syncthreads();
  if (seg == 0) {
    float t = red[0][h];
#pragma unroll
    for (int k = 1; k < 16; ++k) t += red[k][h];
    lg[h] = t + bd2[h];
  }
  __syncthreads();
  if (threadIdx.x < 16) {
    float mx = lg[0];
#pragma unroll
    for (int k = 1; k < 16; ++k) mx = fmaxf(mx, lg[k]);
    float sum = 0.f;
#pragma unroll
    for (int k = 0; k < 16; ++k) sum += __expf(lg[k] - mx);
    dw[bt * 16 + threadIdx.x] = __expf(lg[threadIdx.x] - mx) / sum;
  }
}

// ---------- MFMA attention v2: block per (b,t,h), 4 waves x 16 q-rows ----------
__global__ __launch_bounds__(256) void attn_kernel(
    const unsigned short* __restrict__ Q,   // (BT*64) x 1024, col = h*64+d
    const unsigned short* __restrict__ KV,  // (BT*1025) x 2048, K then V
    const float* __restrict__ dw,           // BT x 16
    unsigned short* __restrict__ AO) {      // (BT*64) x 1024, col = h*64+d
  __shared__ __attribute__((aligned(16))) unsigned short ks[2][64 * 72];  // K: [key][d]
  __shared__ __attribute__((aligned(16))) unsigned short vt[2][64 * 72];  // V^T: [d][perm key]
  const int raw = blockIdx.x;
  const int bt = (raw & 7) * 4 + ((raw >> 3) >> 4);
  const int h  = (raw >> 3) & 15;
  const int tid = threadIdx.x;
  const int lane = tid & 63, wave = tid >> 6;
  const int i16 = lane & 15, quad = lane >> 4;
  const int wrow = wave * 16;

  const unsigned short* qbase =
      Q + ((size_t)(bt * 64 + wrow + i16)) * CINNER + h * 64;
  const short8 bq0 = *(const short8*)(qbase + quad * 8);        // d 0..31
  const short8 bq1 = *(const short8*)(qbase + 32 + quad * 8);   // d 32..63

  const int jrb = tid & 31, seg = tid >> 5;
  const int t_ = jrb & 15, hlf_ = jrb >> 4;
  const int vcol0 = ((t_ >> 2) << 3) + (t_ & 3) + 4 * hlf_;  // + c*32
  const unsigned short* kvb = KV + ((size_t)bt * CNK) * 2048 + h * 64 + seg * 8;

  uint4 kk[2], vv[2];
  auto load_tile = [&](int j0) {
#pragma unroll
    for (int c = 0; c < 2; ++c) {
      const int j = j0 + c * 32 + jrb;
      if (j < CNK) {
        const unsigned short* p = kvb + (size_t)j * 2048;
        kk[c] = *(const uint4*)p;
        vv[c] = *(const uint4*)(p + 1024);
      } else {
        kk[c] = make_uint4(0, 0, 0, 0);
        vv[c] = make_uint4(0, 0, 0, 0);
      }
    }
  };
  auto write_tile = [&](int buf) {
#pragma unroll
    for (int c = 0; c < 2; ++c) {
      const int jr = c * 32 + jrb;
      *(uint4*)&ks[buf][jr * 72 + seg * 8] = kk[c];
      const int vcol = c * 32 + vcol0;
      const unsigned int w[4] = {vv[c].x, vv[c].y, vv[c].z, vv[c].w};
#pragma unroll
      for (int p = 0; p < 4; ++p) {
        vt[buf][(seg * 8 + 2 * p + 0) * 72 + vcol] = (unsigned short)(w[p] & 0xffffu);
        vt[buf][(seg * 8 + 2 * p + 1) * 72 + vcol] = (unsigned short)(w[p] >> 16);
      }
    }
  };

  float l = 0.f;
  floatx4 O[4] = {{0,0,0,0}, {0,0,0,0}, {0,0,0,0}, {0,0,0,0}};
  const float expC = 0.18033688011112042f;  // 0.125 * log2(e)

  load_tile(0);
  write_tile(0);
  constexpr int NT = 17;  // ceil(1025/64)
  for (int t = 0; t < NT; ++t) {
    if (t + 1 < NT) load_tile((t + 1) * 64);
    __syncthreads();
    const int buf = t & 1;
    const unsigned short* ksb = ks[buf];
    const unsigned short* vtb = vt[buf];
#pragma unroll
    for (int c = 0; c < 2; ++c) {
      floatx4 s0 = {0,0,0,0}, s1 = {0,0,0,0};
      const short8 a00 = *(const short8*)&ksb[((2*c)   * 16 + i16) * 72 + quad * 8];
      const short8 a01 = *(const short8*)&ksb[((2*c)   * 16 + i16) * 72 + 32 + quad * 8];
      const short8 a10 = *(const short8*)&ksb[((2*c+1) * 16 + i16) * 72 + quad * 8];
      const short8 a11 = *(const short8*)&ksb[((2*c+1) * 16 + i16) * 72 + 32 + quad * 8];
      s0 = mfma_bf16(a00, bq0, s0); s0 = mfma_bf16(a01, bq1, s0);
      s1 = mfma_bf16(a10, bq0, s1); s1 = mfma_bf16(a11, bq1, s1);
      unsigned short pb0[4], pb1[4];
      if (t == NT - 1) {  // masked tail tile (keys 1024..1087; only 1024 valid)
#pragma unroll
        for (int r = 0; r < 4; ++r) {
          const int k0g = t * 64 + (2*c)   * 16 + quad * 4 + r;
          const int k1g = t * 64 + (2*c+1) * 16 + quad * 4 + r;
          const float p0 = (k0g < CNK) ? exp2f(s0[r] * expC) : 0.f;
          const float p1 = (k1g < CNK) ? exp2f(s1[r] * expC) : 0.f;
          l += p0 + p1;
          pb0[r] = f2bf(p0); pb1[r] = f2bf(p1);
        }
      } else {
#pragma unroll
        for (int r = 0; r < 4; ++r) {
          const float p0 = exp2f(s0[r] * expC);
          const float p1 = exp2f(s1[r] * expC);
          l += p0 + p1;
          pb0[r] = f2bf(p0); pb1[r] = f2bf(p1);
        }
      }
      const short8 bp = {
          (short)pb0[0], (short)pb0[1], (short)pb0[2], (short)pb0[3],
          (short)pb1[0], (short)pb1[1], (short)pb1[2], (short)pb1[3]};
#pragma unroll
      for (int dt = 0; dt < 4; ++dt) {
        const short8 av = *(const short8*)&vtb[(dt * 16 + i16) * 72 + c * 32 + quad * 8];
        O[dt] = mfma_bf16(av, bp, O[dt]);
      }
    }
    if (t + 1 < NT) write_tile((t + 1) & 1);
  }

  l += __shfl_xor(l, 16);
  l += __shfl_xor(l, 32);
  const float wsc = dw[bt * 16 + h] / l;
  unsigned short* obase = AO + ((size_t)(bt * 64 + wrow + i16)) * CINNER + h * 64;
#pragma unroll
  for (int dt = 0; dt < 4; ++dt)
#pragma unroll
    for (int r = 0; r < 4; ++r)
      obase[dt * 16 + quad * 4 + r] = f2bf(O[dt][r] * wsc);
}

// ---------- host ----------
extern "C" void kernel_launch(void* const* d_in, const int* in_sizes, int n_in,
                              void* d_out, int out_size, void* d_ws, size_t ws_size,
                              hipStream_t stream) {
  const float* x       = (const float*)d_in[0];
  const float* latents = (const float*)d_in[1];
  const float* gm  = (const float*)d_in[2];
  const float* bm  = (const float*)d_in[3];
  const float* gl  = (const float*)d_in[4];
  const float* bl  = (const float*)d_in[5];
  const float* Wq  = (const float*)d_in[6];
  const float* Wkv = (const float*)d_in[7];
  const float* Wout= (const float*)d_in[8];
  const float* Wd1 = (const float*)d_in[9];
  const float* bd1 = (const float*)d_in[10];
  const float* Wd2 = (const float*)d_in[11];
  const float* bd2 = (const float*)d_in[12];
  float* out = (float*)d_out;

  char* ws = (char*)d_ws;
  size_t off = 0;
  auto alloc = [&](size_t bytes) -> void* {
    void* p = ws + off;
    off += (bytes + 255) & ~(size_t)255;
    return p;
  };
  unsigned short* xn   = (unsigned short*)alloc((size_t)CBT * CN1 * CD * 2);      // 64 MB
  unsigned short* kv   = (unsigned short*)alloc((size_t)CBT * CNK * 2048 * 2);    // 131 MB
  float*          lnf  = (float*)        alloc((size_t)CBT * CN2 * CD * 4);       // 8 MB
  unsigned short* lnb  = (unsigned short*)alloc((size_t)CBT * CN2 * CD * 2);      // 4 MB
  unsigned short* wqT  = (unsigned short*)alloc((size_t)CD * CINNER * 2);         // 2 MB  [N][K]
  unsigned short* wkvT = (unsigned short*)alloc((size_t)CD * 2 * CINNER * 2);     // 4 MB  [2N][K]
  unsigned short* woT  = (unsigned short*)alloc((size_t)CINNER * CD * 2);         // 2 MB  [N][K]
  unsigned short* qb   = (unsigned short*)alloc((size_t)CBT * CN2 * CINNER * 2);  // 4 MB
  unsigned short* aob  = (unsigned short*)alloc((size_t)CBT * CN2 * CINNER * 2);  // 4 MB
  float*          dwp  = (float*)        alloc((size_t)CBT * CH * 4);
  float*          meanp= (float*)        alloc((size_t)CBT * CD * 4);             // 128 KB
  float*          hidp = (float*)        alloc((size_t)CBT * 256 * 4);            // 32 KB
  if (off > ws_size) return;  // signal: output stays zero (ws too small)

  // 1) layernorms (x -> bf16; latents -> bf16 + fp32)
  ln_kernel<<<CBT * CN1 / 4, 256, 0, stream>>>(x, gm, bm, xn, nullptr);
  ln_kernel<<<CBT * CN2 / 4, 256, 0, stream>>>(latents, gl, bl, lnb, lnf);
  // 2) weight transpose + bf16 convert: W[K][N] -> WT[N][K]
  wtrans_kernel<<<dim3(CINNER / 64, CD / 64), 256, 0, stream>>>(Wq, wqT, CD, CINNER);
  wtrans_kernel<<<dim3(2 * CINNER / 64, CD / 64), 256, 0, stream>>>(Wkv, wkvT, CD, 2 * CINNER);
  wtrans_kernel<<<dim3(CD / 64, CINNER / 64), 256, 0, stream>>>(Wout, woT, CINNER, CD);
  // 3) Q = ln @ Wq   (2048 x 1024 x 1024)
  gemm128_kernel<false, true><<<dim3(1024 / 128, 2048 / 128), 256, 0, stream>>>(
      lnb, nullptr, nullptr, wqT, qb, nullptr, 2048, 1024, 1024);
  // 4) KV = concat(xn, ln[:, :, 0:1]) @ Wkv   (32800 x 2048 x 1024)
  //    256^2 tile, 8 waves, 8-phase counted-vmcnt schedule (m201 port).
  {
    const int MB = (CBT * CNK + 255) / 256;   // 129
    gemm8p_kernel<true><<<MB * 8, 512, 0, stream>>>(
        xn, lnb, wkvT, kv, CBT * CNK, 2048, 1024);
  }
  // 5) dynamic head weights (3-stage, parallel)
  dwmean_kernel<<<CBT * 4, 256, 0, stream>>>(lnf, meanp);
  dwmlp_kernel<<<CBT * 8, 256, 0, stream>>>(meanp, Wd1, bd1, hidp);
  dwfin_kernel<<<CBT, 256, 0, stream>>>(hidp, Wd2, bd2, dwp);
  // 6) attention (512 blocks = BT * H, XCD-grouped by bt)
  attn_kernel<<<CBT * CH, 256, 0, stream>>>(qb, kv, dwp, aob);
  // 7) out = AO @ Wout   (2048 x 1024 x 1024) -> fp32 d_out
  gemm128_kernel<false, false><<<dim3(1024 / 128, 2048 / 128), 256, 0, stream>>>(
      aob, nullptr, nullptr, woT, nullptr, out, 2048, 1024, 1024);
}

// Round 7
// 548.500 us; speedup vs baseline: 1.0982x; 1.0039x over previous
//
#include <hip/hip_runtime.h>
#include <cstdint>
#include <cstddef>

// Problem constants (B=8,T=4,N1=1024,N2=64,D=1024,H=16,DH=64)
constexpr int CB = 8, CT = 4, CN1 = 1024, CN2 = 64, CD = 1024, CH = 16, CDH = 64;
constexpr int CBT = CB * CT;          // 32
constexpr int CNK = CN1 + 1;          // 1025
constexpr int CINNER = CH * CDH;      // 1024

// ---------- bf16 helpers (raw ushort storage) ----------
__device__ __forceinline__ unsigned short f2bf(float f) {
  union { float f; unsigned int u; } v; v.f = f;
  unsigned int u = v.u;
  u += 0x7fffu + ((u >> 16) & 1u);    // RNE
  return (unsigned short)(u >> 16);
}

// ---------- MFMA types ----------
typedef __attribute__((ext_vector_type(8))) short short8;
typedef __attribute__((ext_vector_type(8))) __bf16 bf16x8;
typedef __attribute__((ext_vector_type(4))) float floatx4;

template <typename V>
__device__ __forceinline__ auto mfma_bf16_impl(V a, V b, floatx4 c, int)
    -> decltype(__builtin_amdgcn_mfma_f32_16x16x32_bf16(a, b, c, 0, 0, 0)) {
  return __builtin_amdgcn_mfma_f32_16x16x32_bf16(a, b, c, 0, 0, 0);
}
template <typename V>
__device__ __forceinline__ floatx4 mfma_bf16_impl(V a, V b, floatx4 c, long) {
  return __builtin_amdgcn_mfma_f32_16x16x32_bf16(
      __builtin_bit_cast(bf16x8, a), __builtin_bit_cast(bf16x8, b), c, 0, 0, 0);
}
__device__ __forceinline__ floatx4 mfma_bf16(short8 a, short8 b, floatx4 c) {
  return mfma_bf16_impl(a, b, c, 0);
}

// ---------- async global->LDS (16B/lane), guarded w/ manual fallback ----------
#if __has_builtin(__builtin_amdgcn_global_load_lds)
#define HAS_GLDS 1
__device__ __forceinline__ void glds16(const unsigned short* g, unsigned short* l) {
  __builtin_amdgcn_global_load_lds(
      (const __attribute__((address_space(1))) void*)g,
      (__attribute__((address_space(3))) void*)l, 16, 0, 0);
}
#else
#define HAS_GLDS 0
#endif

#define FENCEV(n) asm volatile("s_waitcnt vmcnt(" #n ")" ::: "memory")
#define SBAR __builtin_amdgcn_s_barrier()
#define LGKM0 do { asm volatile("s_waitcnt lgkmcnt(0)" ::: "memory"); \
                   __builtin_amdgcn_sched_barrier(0); } while (0)

// ---------- LayerNorm: one WAVE per row of D=1024; 4 rows/block ----------
__global__ __launch_bounds__(256) void ln_kernel(
    const float* __restrict__ x, const float* __restrict__ g,
    const float* __restrict__ b, unsigned short* __restrict__ obf,
    float* __restrict__ of32) {
  const int row = blockIdx.x * 4 + (threadIdx.x >> 6);
  const int lane = threadIdx.x & 63;
  const float4* xr = (const float4*)(x + (size_t)row * CD);
  float4 v[4];
#pragma unroll
  for (int k = 0; k < 4; ++k) v[k] = xr[lane + 64 * k];
  float s = 0.f, s2 = 0.f;
#pragma unroll
  for (int k = 0; k < 4; ++k) {
    s  += v[k].x + v[k].y + v[k].z + v[k].w;
    s2 += v[k].x*v[k].x + v[k].y*v[k].y + v[k].z*v[k].z + v[k].w*v[k].w;
  }
#pragma unroll
  for (int off = 32; off; off >>= 1) { s += __shfl_xor(s, off); s2 += __shfl_xor(s2, off); }
  const float mean = s * (1.0f / 1024.0f);
  const float var  = s2 * (1.0f / 1024.0f) - mean * mean;   // == jnp.var (ddof=0)
  const float rstd = rsqrtf(var + 1e-5f);
#pragma unroll
  for (int k = 0; k < 4; ++k) {
    const float4 gv = ((const float4*)g)[lane + 64 * k];
    const float4 bv = ((const float4*)b)[lane + 64 * k];
    float4 y;
    y.x = (v[k].x - mean) * rstd * gv.x + bv.x;
    y.y = (v[k].y - mean) * rstd * gv.y + bv.y;
    y.z = (v[k].z - mean) * rstd * gv.z + bv.z;
    y.w = (v[k].w - mean) * rstd * gv.w + bv.w;
    ushort4 o; o.x = f2bf(y.x); o.y = f2bf(y.y); o.z = f2bf(y.z); o.w = f2bf(y.w);
    ((ushort4*)(obf + (size_t)row * CD))[lane + 64 * k] = o;
    if (of32) ((float4*)(of32 + (size_t)row * CD))[lane + 64 * k] = y;
  }
}

// ---------- weight transpose + bf16 convert: W[K][N] f32 -> WT[N][K] bf16 ----
__global__ __launch_bounds__(256) void wtrans_kernel(
    const float* __restrict__ W, unsigned short* __restrict__ WT, int K, int N) {
  __shared__ float t[64][65];
  const int n0 = blockIdx.x * 64, k0 = blockIdx.y * 64;
  const int tid = threadIdx.x;
  const int kr = tid >> 4, ns = (tid & 15) * 4;
#pragma unroll
  for (int i = 0; i < 4; ++i) {
    const int k = kr + i * 16;
    const float4 v = *(const float4*)&W[(size_t)(k0 + k) * N + n0 + ns];
    t[k][ns + 0] = v.x; t[k][ns + 1] = v.y; t[k][ns + 2] = v.z; t[k][ns + 3] = v.w;
  }
  __syncthreads();
  const int n = tid >> 2, ks = (tid & 3) * 16;
#pragma unroll
  for (int c = 0; c < 4; ++c) {
    ushort4 o;
    o.x = f2bf(t[ks + c * 4 + 0][n]);
    o.y = f2bf(t[ks + c * 4 + 1][n]);
    o.z = f2bf(t[ks + c * 4 + 2][n]);
    o.w = f2bf(t[ks + c * 4 + 3][n]);
    *(ushort4*)&WT[(size_t)(n0 + n) * K + k0 + ks + c * 4] = o;
  }
}

// ---------- m97-structure GEMM: C[M,N] = A[M,K] @ BT[N,K]^T (Q/out GEMMs) ----
template <bool A_KV, bool C_BF16>
__global__ __launch_bounds__(256) void gemm128_kernel(
    const unsigned short* __restrict__ A, const unsigned short* __restrict__ xn,
    const unsigned short* __restrict__ lnb, const unsigned short* __restrict__ BT,
    unsigned short* __restrict__ Cb, float* __restrict__ Cf,
    int M, int N, int K) {
  __shared__ __attribute__((aligned(16))) unsigned short As[128 * 32];
  __shared__ __attribute__((aligned(16))) unsigned short Bs[128 * 32];
  const int tid = threadIdx.x;
  const int col0 = blockIdx.x * 128, row0 = blockIdx.y * 128;
  const int srow = tid >> 2, skseg = (tid & 3) * 8;

  auto arow_ptr = [&](int grow) -> const unsigned short* {
    if (grow >= M) grow = M - 1;
    if (A_KV) {
      const int bt = grow / CNK, j = grow - bt * CNK;
      return (j < CN1) ? xn + ((size_t)(bt * CN1 + j)) * K + skseg
                       : lnb + ((size_t)(bt * CN2)) * K + skseg;  // ln[:, :, 0]
    }
    return A + (size_t)grow * K + skseg;
  };
  const unsigned short* a0 = arow_ptr(row0 + srow);
  const unsigned short* a1 = arow_ptr(row0 + 64 + srow);
  const unsigned short* b0 = BT + (size_t)(col0 + srow) * K + skseg;
  const unsigned short* b1 = BT + (size_t)(col0 + 64 + srow) * K + skseg;

  const int lane = tid & 63, wave = tid >> 6;
  const int wrow = (wave >> 1) * 64, wcol = (wave & 1) * 64;
  const int i16 = lane & 15, quad = lane >> 4;

  floatx4 acc[4][4] = {};
  for (int kt = 0; kt < K; kt += 32) {
    __syncthreads();
#if HAS_GLDS
    glds16(a0 + kt, &As[tid * 8]);
    glds16(a1 + kt, &As[2048 + tid * 8]);
    glds16(b0 + kt, &Bs[tid * 8]);
    glds16(b1 + kt, &Bs[2048 + tid * 8]);
#else
    *(uint4*)&As[tid * 8]        = *(const uint4*)(a0 + kt);
    *(uint4*)&As[2048 + tid * 8] = *(const uint4*)(a1 + kt);
    *(uint4*)&Bs[tid * 8]        = *(const uint4*)(b0 + kt);
    *(uint4*)&Bs[2048 + tid * 8] = *(const uint4*)(b1 + kt);
#endif
    __syncthreads();
    short8 af[4], bf[4];
#pragma unroll
    for (int ti = 0; ti < 4; ++ti)
      af[ti] = *(const short8*)&As[(wrow + ti * 16 + i16) * 32 + quad * 8];
#pragma unroll
    for (int tj = 0; tj < 4; ++tj)
      bf[tj] = *(const short8*)&Bs[(wcol + tj * 16 + i16) * 32 + quad * 8];
#pragma unroll
    for (int ti = 0; ti < 4; ++ti)
#pragma unroll
      for (int tj = 0; tj < 4; ++tj)
        acc[ti][tj] = mfma_bf16(af[ti], bf[tj], acc[ti][tj]);
  }
#pragma unroll
  for (int ti = 0; ti < 4; ++ti)
#pragma unroll
    for (int tj = 0; tj < 4; ++tj) {
      const int gc = col0 + wcol + tj * 16 + i16;
#pragma unroll
      for (int r = 0; r < 4; ++r) {
        const int gr = row0 + wrow + ti * 16 + quad * 4 + r;
        if (gr < M) {
          if (C_BF16) Cb[(size_t)gr * N + gc] = f2bf(acc[ti][tj][r]);
          else        Cf[(size_t)gr * N + gc] = acc[ti][tj][r];
        }
      }
    }
}

// ---------- KV GEMM: 256^2 tile, 8 waves, 8-PHASE schedule (m201 port) ------
// r6 post-mortem: schedule is correct (passed, conflicts 0) but the XCD
// mapping nb=blockIdx&7 streamed ALL of A (67 MB) through every XCD's L2 ->
// FETCH 287 MB, fill-traffic-bound at 2.18 TB/s. THIS ROUND: restore the
// r1-measured-good bijective swizzle (each XCD owns a contiguous mb range;
// A row-panels XCD-local, reused across all 8 nb; B 4 MB L2-resident).
// r1 measured 109 MB FETCH with this mapping on the same grid shape.
//
// Schedule (unchanged from r6): 2 K-tiles (BK=64) per iteration, 8 phases:
//   {<=12 ds_read_b128 || stage one 16KB half-tile (2 glds)} ; BAR ;
//   lgkmcnt(0)+sched_barrier ; setprio(1) ; 16 MFMA ; setprio(0) ; BAR
// Counted vmcnt never 0 in steady state: vmcnt(4) before BAR_b of ph4/ph8;
// prologue 6 half-tiles + vmcnt(4); last iteration peeled with vmcnt(0).
// Swizzle (both-sides): read slot = (ks*4+quad) ^ (row&7); staging keeps LDS
// dest lane-linear (glds) and applies the involution to the GLOBAL source.
template <bool A_KV>
__global__ __launch_bounds__(512, 2) void gemm8p_kernel(
    const unsigned short* __restrict__ xn, const unsigned short* __restrict__ lnb,
    const unsigned short* __restrict__ BT, unsigned short* __restrict__ Cb,
    int M, int N, int K) {
  __shared__ __attribute__((aligned(16))) unsigned short As[2][2][128 * 64];
  __shared__ __attribute__((aligned(16))) unsigned short Bs[2][2][128 * 64];
  const int tid = threadIdx.x;
  // bijective XCD swizzle (grid = 129*8, cpx = 129): each XCD gets a
  // contiguous virt range => contiguous mb range with nb cycling fastest.
  const int raw = blockIdx.x;
  const int cpx = gridDim.x >> 3;
  const int virt = (raw & 7) * cpx + (raw >> 3);
  const int mb = virt >> 3, nb = virt & 7;
  const int row0 = mb * 256, col0 = nb * 256;

  auto arow = [&](int grow) -> const unsigned short* {
    if (grow >= M) grow = M - 1;
    if (A_KV) {
      const int bt = grow / CNK, j = grow - bt * CNK;
      return (j < CN1) ? xn + ((size_t)(bt * CN1 + j)) * K
                       : lnb + ((size_t)(bt * CN2)) * K;   // ln[:, :, 0]
    }
    return (const unsigned short*)nullptr;  // unused
  };

  // staging sources: thread t covers chunks t and t+512 of each 16KB half
  // (128 rows x 64 shorts). chunk c -> row c>>3, dest slot c&7; source slot
  // = (c&7) ^ (row&7). Same source-slot for both chunks (row diff = 64).
  const int rr0 = tid >> 3;                 // 0..63
  const int sl  = (tid & 7) ^ (rr0 & 7);
  const unsigned short* pA[2][2];
  const unsigned short* pB[2][2];
#pragma unroll
  for (int h = 0; h < 2; ++h)
#pragma unroll
    for (int c = 0; c < 2; ++c) {
      pA[h][c] = arow(row0 + h * 128 + rr0 + c * 64) + sl * 8;
      pB[h][c] = BT + (size_t)(col0 + h * 128 + rr0 + c * 64) * K + sl * 8;
    }

  auto stageA = [&](int buf, int h, int t) {
    unsigned short* d = &As[buf][h][tid * 8];
#if HAS_GLDS
    glds16(pA[h][0] + t * 64, d);
    glds16(pA[h][1] + t * 64, d + 4096);
#else
    *(uint4*)d          = *(const uint4*)(pA[h][0] + t * 64);
    *(uint4*)(d + 4096) = *(const uint4*)(pA[h][1] + t * 64);
#endif
  };
  auto stageB = [&](int buf, int h, int t) {
    unsigned short* d = &Bs[buf][h][tid * 8];
#if HAS_GLDS
    glds16(pB[h][0] + t * 64, d);
    glds16(pB[h][1] + t * 64, d + 4096);
#else
    *(uint4*)d          = *(const uint4*)(pB[h][0] + t * 64);
    *(uint4*)(d + 4096) = *(const uint4*)(pB[h][1] + t * 64);
#endif
  };

  const int lane = tid & 63, wave = tid >> 6;
  const int wr = wave >> 2, wc = wave & 3;      // 2M x 4N; per-wave 128x64
  const int i16 = lane & 15, quad = lane >> 4;
  const int sw = i16 & 7;
  const int slk0 = (quad ^ sw) * 8;             // ks=0: slot (0*4+quad)^sw
  const int slk1 = ((4 + quad) ^ sw) * 8;       // ks=1: slot (4+quad)^sw
  const int brow = (wc & 1) * 64;

  short8 aA[8], bB[8];
  floatx4 acc[8][4] = {};

  auto readA4 = [&](const unsigned short* Ah, int mlo) {
#pragma unroll
    for (int i = 0; i < 4; ++i) {
      const int base = ((mlo + i) * 16 + i16) * 64;
      aA[i * 2 + 0] = *(const short8*)(Ah + base + slk0);
      aA[i * 2 + 1] = *(const short8*)(Ah + base + slk1);
    }
  };
  auto readB2 = [&](const unsigned short* Bh, int nlo) {
#pragma unroll
    for (int j = 0; j < 2; ++j) {
      const int base = (brow + (nlo + j) * 16 + i16) * 64;
      bB[(nlo + j) * 2 + 0] = *(const short8*)(Bh + base + slk0);
      bB[(nlo + j) * 2 + 1] = *(const short8*)(Bh + base + slk1);
    }
  };
  auto mfmaQ = [&](int mlo, int nlo) {
    __builtin_amdgcn_s_setprio(1);
#pragma unroll
    for (int i = 0; i < 4; ++i)
#pragma unroll
      for (int j = 0; j < 2; ++j) {
        acc[mlo + i][nlo + j] =
            mfma_bf16(aA[i * 2 + 0], bB[(nlo + j) * 2 + 0], acc[mlo + i][nlo + j]);
        acc[mlo + i][nlo + j] =
            mfma_bf16(aA[i * 2 + 1], bB[(nlo + j) * 2 + 1], acc[mlo + i][nlo + j]);
      }
    __builtin_amdgcn_s_setprio(0);
  };

  // prologue: tile0 all 4 halves + tile1 heads; vmcnt(4) keeps the 2 newest
  // half-tiles (tile1 heads) in flight, drains tile0.
  stageB(0, 0, 0); stageA(0, 0, 0); stageB(0, 1, 0); stageA(0, 1, 0);
  stageB(1, 0, 1); stageA(1, 0, 1);
  FENCEV(4);
  SBAR;

  const unsigned short* A0 = &As[0][wr][0];
  const unsigned short* B0 = &Bs[0][wc >> 1][0];
  const unsigned short* A1 = &As[1][wr][0];
  const unsigned short* B1 = &Bs[1][wc >> 1][0];

  auto iter = [&](int t, bool full) {
    // ---- tile t (buffer 0) ----
    // ph1: Q(m0-3, n0-1)
    readB2(B0, 0); readA4(A0, 0);
    stageB(1, 1, t + 1);
    SBAR; LGKM0;
    mfmaQ(0, 0);
    SBAR;
    // ph2: Q(m0-3, n2-3)
    readB2(B0, 2);
    stageA(1, 1, t + 1);
    SBAR; LGKM0;
    mfmaQ(0, 2);
    SBAR;
    // ph3: Q(m4-7, n0-1)
    readA4(A0, 4);
    if (full) stageB(0, 0, t + 2);
    SBAR; LGKM0;
    mfmaQ(4, 0);
    SBAR;
    // ph4: Q(m4-7, n2-3) -- no reads
    if (full) stageA(0, 0, t + 2);
    SBAR;
    mfmaQ(4, 2);
    if (full) { FENCEV(4); } else { FENCEV(0); }
    SBAR;
    // ---- tile t+1 (buffer 1) ----
    // ph5
    readB2(B1, 0); readA4(A1, 0);
    if (full) stageB(0, 1, t + 2);
    SBAR; LGKM0;
    mfmaQ(0, 0);
    SBAR;
    // ph6
    readB2(B1, 2);
    if (full) stageA(0, 1, t + 2);
    SBAR; LGKM0;
    mfmaQ(0, 2);
    SBAR;
    // ph7
    readA4(A1, 4);
    if (full) stageB(1, 0, t + 3);
    SBAR; LGKM0;
    mfmaQ(4, 0);
    SBAR;
    // ph8 -- no reads
    if (full) stageA(1, 0, t + 3);
    SBAR;
    mfmaQ(4, 2);
    if (full) FENCEV(4);
    SBAR;
  };

  const int NT = K >> 6;                  // 16 K-tiles of 64
  for (int t = 0; t + 2 < NT; t += 2) iter(t, true);
  iter(NT - 2, false);

#pragma unroll
  for (int m = 0; m < 8; ++m)
#pragma unroll
    for (int n = 0; n < 4; ++n) {
      const int gc = col0 + wc * 64 + n * 16 + i16;
#pragma unroll
      for (int r = 0; r < 4; ++r) {
        const int gr = row0 + wr * 128 + m * 16 + quad * 4 + r;
        if (gr < M) Cb[(size_t)gr * N + gc] = f2bf(acc[m][n][r]);
      }
    }
}

// ---------- dynamic head weights, stage 1: mean over latent rows ----------
__global__ __launch_bounds__(256) void dwmean_kernel(
    const float* __restrict__ lnf, float* __restrict__ meanp) {
  const int bt = blockIdx.x >> 2, dseg = blockIdx.x & 3;
  const int d = dseg * 256 + threadIdx.x;
  const float* base = lnf + (size_t)bt * CN2 * CD + d;
  float s = 0.f;
#pragma unroll 4
  for (int r = 0; r < CN2; ++r) s += base[(size_t)r * CD];
  meanp[bt * CD + d] = s * (1.0f / 64.0f);
}

// ---------- dw stage 2: hid = relu(mean @ Wd1 + bd1) ----------
__global__ __launch_bounds__(256) void dwmlp_kernel(
    const float* __restrict__ meanp, const float* __restrict__ Wd1,
    const float* __restrict__ bd1, float* __restrict__ hidp) {
  __shared__ float red[8][32];
  const int bt = blockIdx.x >> 3, og = blockIdx.x & 7;
  const int o = threadIdx.x & 31, seg = threadIdx.x >> 5;
  const int col = og * 32 + o;
  const float* mb = meanp + bt * CD;
  float s = 0.f;
#pragma unroll 4
  for (int d = seg * 128; d < seg * 128 + 128; ++d)
    s += mb[d] * Wd1[(size_t)d * 256 + col];
  red[seg][o] = s;
  __syncthreads();
  if (seg == 0) {
    float t = red[0][o];
#pragma unroll
    for (int k = 1; k < 8; ++k) t += red[k][o];
    hidp[bt * 256 + col] = fmaxf(t + bd1[col], 0.0f);
  }
}

// ---------- dw stage 3: dw = softmax(hid @ Wd2 + bd2) ----------
__global__ __launch_bounds__(256) void dwfin_kernel(
    const float* __restrict__ hidp, const float* __restrict__ Wd2,
    const float* __restrict__ bd2, float* __restrict__ dw) {
  __shared__ float red[16][16];
  __shared__ float lg[16];
  const int bt = blockIdx.x;
  const int h = threadIdx.x & 15, seg = threadIdx.x >> 4;
  const float* hb = hidp + bt * 256;
  float s = 0.f;
#pragma unroll
  for (int o = seg * 16; o < seg * 16 + 16; ++o)
    s += hb[o] * Wd2[o * 16 + h];
  red[seg][h] = s;
  __syncthreads();
  if (seg == 0) {
    float t = red[0][h];
#pragma unroll
    for (int k = 1; k < 16; ++k) t += red[k][h];
    lg[h] = t + bd2[h];
  }
  __syncthreads();
  if (threadIdx.x < 16) {
    float mx = lg[0];
#pragma unroll
    for (int k = 1; k < 16; ++k) mx = fmaxf(mx, lg[k]);
    float sum = 0.f;
#pragma unroll
    for (int k = 0; k < 16; ++k) sum += __expf(lg[k] - mx);
    dw[bt * 16 + threadIdx.x] = __expf(lg[threadIdx.x] - mx) / sum;
  }
}

// ---------- MFMA attention v2: block per (b,t,h), 4 waves x 16 q-rows ----------
__global__ __launch_bounds__(256) void attn_kernel(
    const unsigned short* __restrict__ Q,   // (BT*64) x 1024, col = h*64+d
    const unsigned short* __restrict__ KV,  // (BT*1025) x 2048, K then V
    const float* __restrict__ dw,           // BT x 16
    unsigned short* __restrict__ AO) {      // (BT*64) x 1024, col = h*64+d
  __shared__ __attribute__((aligned(16))) unsigned short ks[2][64 * 72];  // K: [key][d]
  __shared__ __attribute__((aligned(16))) unsigned short vt[2][64 * 72];  // V^T: [d][perm key]
  const int raw = blockIdx.x;
  const int bt = (raw & 7) * 4 + ((raw >> 3) >> 4);
  const int h  = (raw >> 3) & 15;
  const int tid = threadIdx.x;
  const int lane = tid & 63, wave = tid >> 6;
  const int i16 = lane & 15, quad = lane >> 4;
  const int wrow = wave * 16;

  const unsigned short* qbase =
      Q + ((size_t)(bt * 64 + wrow + i16)) * CINNER + h * 64;
  const short8 bq0 = *(const short8*)(qbase + quad * 8);        // d 0..31
  const short8 bq1 = *(const short8*)(qbase + 32 + quad * 8);   // d 32..63

  const int jrb = tid & 31, seg = tid >> 5;
  const int t_ = jrb & 15, hlf_ = jrb >> 4;
  const int vcol0 = ((t_ >> 2) << 3) + (t_ & 3) + 4 * hlf_;  // + c*32
  const unsigned short* kvb = KV + ((size_t)bt * CNK) * 2048 + h * 64 + seg * 8;

  uint4 kk[2], vv[2];
  auto load_tile = [&](int j0) {
#pragma unroll
    for (int c = 0; c < 2; ++c) {
      const int j = j0 + c * 32 + jrb;
      if (j < CNK) {
        const unsigned short* p = kvb + (size_t)j * 2048;
        kk[c] = *(const uint4*)p;
        vv[c] = *(const uint4*)(p + 1024);
      } else {
        kk[c] = make_uint4(0, 0, 0, 0);
        vv[c] = make_uint4(0, 0, 0, 0);
      }
    }
  };
  auto write_tile = [&](int buf) {
#pragma unroll
    for (int c = 0; c < 2; ++c) {
      const int jr = c * 32 + jrb;
      *(uint4*)&ks[buf][jr * 72 + seg * 8] = kk[c];
      const int vcol = c * 32 + vcol0;
      const unsigned int w[4] = {vv[c].x, vv[c].y, vv[c].z, vv[c].w};
#pragma unroll
      for (int p = 0; p < 4; ++p) {
        vt[buf][(seg * 8 + 2 * p + 0) * 72 + vcol] = (unsigned short)(w[p] & 0xffffu);
        vt[buf][(seg * 8 + 2 * p + 1) * 72 + vcol] = (unsigned short)(w[p] >> 16);
      }
    }
  };

  float l = 0.f;
  floatx4 O[4] = {{0,0,0,0}, {0,0,0,0}, {0,0,0,0}, {0,0,0,0}};
  const float expC = 0.18033688011112042f;  // 0.125 * log2(e)

  load_tile(0);
  write_tile(0);
  constexpr int NT = 17;  // ceil(1025/64)
  for (int t = 0; t < NT; ++t) {
    if (t + 1 < NT) load_tile((t + 1) * 64);
    __syncthreads();
    const int buf = t & 1;
    const unsigned short* ksb = ks[buf];
    const unsigned short* vtb = vt[buf];
#pragma unroll
    for (int c = 0; c < 2; ++c) {
      floatx4 s0 = {0,0,0,0}, s1 = {0,0,0,0};
      const short8 a00 = *(const short8*)&ksb[((2*c)   * 16 + i16) * 72 + quad * 8];
      const short8 a01 = *(const short8*)&ksb[((2*c)   * 16 + i16) * 72 + 32 + quad * 8];
      const short8 a10 = *(const short8*)&ksb[((2*c+1) * 16 + i16) * 72 + quad * 8];
      const short8 a11 = *(const short8*)&ksb[((2*c+1) * 16 + i16) * 72 + 32 + quad * 8];
      s0 = mfma_bf16(a00, bq0, s0); s0 = mfma_bf16(a01, bq1, s0);
      s1 = mfma_bf16(a10, bq0, s1); s1 = mfma_bf16(a11, bq1, s1);
      unsigned short pb0[4], pb1[4];
      if (t == NT - 1) {  // masked tail tile (keys 1024..1087; only 1024 valid)
#pragma unroll
        for (int r = 0; r < 4; ++r) {
          const int k0g = t * 64 + (2*c)   * 16 + quad * 4 + r;
          const int k1g = t * 64 + (2*c+1) * 16 + quad * 4 + r;
          const float p0 = (k0g < CNK) ? exp2f(s0[r] * expC) : 0.f;
          const float p1 = (k1g < CNK) ? exp2f(s1[r] * expC) : 0.f;
          l += p0 + p1;
          pb0[r] = f2bf(p0); pb1[r] = f2bf(p1);
        }
      } else {
#pragma unroll
        for (int r = 0; r < 4; ++r) {
          const float p0 = exp2f(s0[r] * expC);
          const float p1 = exp2f(s1[r] * expC);
          l += p0 + p1;
          pb0[r] = f2bf(p0); pb1[r] = f2bf(p1);
        }
      }
      const short8 bp = {
          (short)pb0[0], (short)pb0[1], (short)pb0[2], (short)pb0[3],
          (short)pb1[0], (short)pb1[1], (short)pb1[2], (short)pb1[3]};
#pragma unroll
      for (int dt = 0; dt < 4; ++dt) {
        const short8 av = *(const short8*)&vtb[(dt * 16 + i16) * 72 + c * 32 + quad * 8];
        O[dt] = mfma_bf16(av, bp, O[dt]);
      }
    }
    if (t + 1 < NT) write_tile((t + 1) & 1);
  }

  l += __shfl_xor(l, 16);
  l += __shfl_xor(l, 32);
  const float wsc = dw[bt * 16 + h] / l;
  unsigned short* obase = AO + ((size_t)(bt * 64 + wrow + i16)) * CINNER + h * 64;
#pragma unroll
  for (int dt = 0; dt < 4; ++dt)
#pragma unroll
    for (int r = 0; r < 4; ++r)
      obase[dt * 16 + quad * 4 + r] = f2bf(O[dt][r] * wsc);
}

// ---------- host ----------
extern "C" void kernel_launch(void* const* d_in, const int* in_sizes, int n_in,
                              void* d_out, int out_size, void* d_ws, size_t ws_size,
                              hipStream_t stream) {
  const float* x       = (const float*)d_in[0];
  const float* latents = (const float*)d_in[1];
  const float* gm  = (const float*)d_in[2];
  const float* bm  = (const float*)d_in[3];
  const float* gl  = (const float*)d_in[4];
  const float* bl  = (const float*)d_in[5];
  const float* Wq  = (const float*)d_in[6];
  const float* Wkv = (const float*)d_in[7];
  const float* Wout= (const float*)d_in[8];
  const float* Wd1 = (const float*)d_in[9];
  const float* bd1 = (const float*)d_in[10];
  const float* Wd2 = (const float*)d_in[11];
  const float* bd2 = (const float*)d_in[12];
  float* out = (float*)d_out;

  char* ws = (char*)d_ws;
  size_t off = 0;
  auto alloc = [&](size_t bytes) -> void* {
    void* p = ws + off;
    off += (bytes + 255) & ~(size_t)255;
    return p;
  };
  unsigned short* xn   = (unsigned short*)alloc((size_t)CBT * CN1 * CD * 2);      // 64 MB
  unsigned short* kv   = (unsigned short*)alloc((size_t)CBT * CNK * 2048 * 2);    // 131 MB
  float*          lnf  = (float*)        alloc((size_t)CBT * CN2 * CD * 4);       // 8 MB
  unsigned short* lnb  = (unsigned short*)alloc((size_t)CBT * CN2 * CD * 2);      // 4 MB
  unsigned short* wqT  = (unsigned short*)alloc((size_t)CD * CINNER * 2);         // 2 MB  [N][K]
  unsigned short* wkvT = (unsigned short*)alloc((size_t)CD * 2 * CINNER * 2);     // 4 MB  [2N][K]
  unsigned short* woT  = (unsigned short*)alloc((size_t)CINNER * CD * 2);         // 2 MB  [N][K]
  unsigned short* qb   = (unsigned short*)alloc((size_t)CBT * CN2 * CINNER * 2);  // 4 MB
  unsigned short* aob  = (unsigned short*)alloc((size_t)CBT * CN2 * CINNER * 2);  // 4 MB
  float*          dwp  = (float*)        alloc((size_t)CBT * CH * 4);
  float*          meanp= (float*)        alloc((size_t)CBT * CD * 4);             // 128 KB
  float*          hidp = (float*)        alloc((size_t)CBT * 256 * 4);            // 32 KB
  if (off > ws_size) return;  // signal: output stays zero (ws too small)

  // 1) layernorms (x -> bf16; latents -> bf16 + fp32)
  ln_kernel<<<CBT * CN1 / 4, 256, 0, stream>>>(x, gm, bm, xn, nullptr);
  ln_kernel<<<CBT * CN2 / 4, 256, 0, stream>>>(latents, gl, bl, lnb, lnf);
  // 2) weight transpose + bf16 convert: W[K][N] -> WT[N][K]
  wtrans_kernel<<<dim3(CINNER / 64, CD / 64), 256, 0, stream>>>(Wq, wqT, CD, CINNER);
  wtrans_kernel<<<dim3(2 * CINNER / 64, CD / 64), 256, 0, stream>>>(Wkv, wkvT, CD, 2 * CINNER);
  wtrans_kernel<<<dim3(CD / 64, CINNER / 64), 256, 0, stream>>>(Wout, woT, CINNER, CD);
  // 3) Q = ln @ Wq   (2048 x 1024 x 1024)
  gemm128_kernel<false, true><<<dim3(1024 / 128, 2048 / 128), 256, 0, stream>>>(
      lnb, nullptr, nullptr, wqT, qb, nullptr, 2048, 1024, 1024);
  // 4) KV = concat(xn, ln[:, :, 0:1]) @ Wkv   (32800 x 2048 x 1024)
  //    256^2 tile, 8 waves, 8-phase counted-vmcnt schedule, r1-style XCD map.
  {
    const int MB = (CBT * CNK + 255) / 256;   // 129
    gemm8p_kernel<true><<<MB * 8, 512, 0, stream>>>(
        xn, lnb, wkvT, kv, CBT * CNK, 2048, 1024);
  }
  // 5) dynamic head weights (3-stage, parallel)
  dwmean_kernel<<<CBT * 4, 256, 0, stream>>>(lnf, meanp);
  dwmlp_kernel<<<CBT * 8, 256, 0, stream>>>(meanp, Wd1, bd1, hidp);
  dwfin_kernel<<<CBT, 256, 0, stream>>>(hidp, Wd2, bd2, dwp);
  // 6) attention (512 blocks = BT * H, XCD-grouped by bt)
  attn_kernel<<<CBT * CH, 256, 0, stream>>>(qb, kv, dwp, aob);
  // 7) out = AO @ Wout   (2048 x 1024 x 1024) -> fp32 d_out
  gemm128_kernel<false, false><<<dim3(1024 / 128, 2048 / 128), 256, 0, stream>>>(
      aob, nullptr, nullptr, woT, nullptr, out, 2048, 1024, 1024);
}

// Round 8
// 524.032 us; speedup vs baseline: 1.1495x; 1.0467x over previous
//
#include <hip/hip_runtime.h>
#include <cstdint>
#include <cstddef>

// Problem constants (B=8,T=4,N1=1024,N2=64,D=1024,H=16,DH=64)
constexpr int CB = 8, CT = 4, CN1 = 1024, CN2 = 64, CD = 1024, CH = 16, CDH = 64;
constexpr int CBT = CB * CT;          // 32
constexpr int CNK = CN1 + 1;          // 1025
constexpr int CINNER = CH * CDH;      // 1024

// ---------- bf16 helpers (raw ushort storage) ----------
__device__ __forceinline__ unsigned short f2bf(float f) {
  union { float f; unsigned int u; } v; v.f = f;
  unsigned int u = v.u;
  u += 0x7fffu + ((u >> 16) & 1u);    // RNE
  return (unsigned short)(u >> 16);
}

// ---------- MFMA types ----------
typedef __attribute__((ext_vector_type(8))) short short8;
typedef __attribute__((ext_vector_type(8))) __bf16 bf16x8;
typedef __attribute__((ext_vector_type(4))) float floatx4;

template <typename V>
__device__ __forceinline__ auto mfma_bf16_impl(V a, V b, floatx4 c, int)
    -> decltype(__builtin_amdgcn_mfma_f32_16x16x32_bf16(a, b, c, 0, 0, 0)) {
  return __builtin_amdgcn_mfma_f32_16x16x32_bf16(a, b, c, 0, 0, 0);
}
template <typename V>
__device__ __forceinline__ floatx4 mfma_bf16_impl(V a, V b, floatx4 c, long) {
  return __builtin_amdgcn_mfma_f32_16x16x32_bf16(
      __builtin_bit_cast(bf16x8, a), __builtin_bit_cast(bf16x8, b), c, 0, 0, 0);
}
__device__ __forceinline__ floatx4 mfma_bf16(short8 a, short8 b, floatx4 c) {
  return mfma_bf16_impl(a, b, c, 0);
}

// ---------- async global->LDS (16B/lane), guarded w/ manual fallback ----------
#if __has_builtin(__builtin_amdgcn_global_load_lds)
#define HAS_GLDS 1
__device__ __forceinline__ void glds16(const unsigned short* g, unsigned short* l) {
  __builtin_amdgcn_global_load_lds(
      (const __attribute__((address_space(1))) void*)g,
      (__attribute__((address_space(3))) void*)l, 16, 0, 0);
}
#else
#define HAS_GLDS 0
#endif

#define FENCEV(n) asm volatile("s_waitcnt vmcnt(" #n ")" ::: "memory")
#define SBAR __builtin_amdgcn_s_barrier()

// ---------- LayerNorm: one WAVE per row of D=1024; 4 rows/block ----------
__global__ __launch_bounds__(256) void ln_kernel(
    const float* __restrict__ x, const float* __restrict__ g,
    const float* __restrict__ b, unsigned short* __restrict__ obf,
    float* __restrict__ of32) {
  const int row = blockIdx.x * 4 + (threadIdx.x >> 6);
  const int lane = threadIdx.x & 63;
  const float4* xr = (const float4*)(x + (size_t)row * CD);
  float4 v[4];
#pragma unroll
  for (int k = 0; k < 4; ++k) v[k] = xr[lane + 64 * k];
  float s = 0.f, s2 = 0.f;
#pragma unroll
  for (int k = 0; k < 4; ++k) {
    s  += v[k].x + v[k].y + v[k].z + v[k].w;
    s2 += v[k].x*v[k].x + v[k].y*v[k].y + v[k].z*v[k].z + v[k].w*v[k].w;
  }
#pragma unroll
  for (int off = 32; off; off >>= 1) { s += __shfl_xor(s, off); s2 += __shfl_xor(s2, off); }
  const float mean = s * (1.0f / 1024.0f);
  const float var  = s2 * (1.0f / 1024.0f) - mean * mean;   // == jnp.var (ddof=0)
  const float rstd = rsqrtf(var + 1e-5f);
#pragma unroll
  for (int k = 0; k < 4; ++k) {
    const float4 gv = ((const float4*)g)[lane + 64 * k];
    const float4 bv = ((const float4*)b)[lane + 64 * k];
    float4 y;
    y.x = (v[k].x - mean) * rstd * gv.x + bv.x;
    y.y = (v[k].y - mean) * rstd * gv.y + bv.y;
    y.z = (v[k].z - mean) * rstd * gv.z + bv.z;
    y.w = (v[k].w - mean) * rstd * gv.w + bv.w;
    ushort4 o; o.x = f2bf(y.x); o.y = f2bf(y.y); o.z = f2bf(y.z); o.w = f2bf(y.w);
    ((ushort4*)(obf + (size_t)row * CD))[lane + 64 * k] = o;
    if (of32) ((float4*)(of32 + (size_t)row * CD))[lane + 64 * k] = y;
  }
}

// ---------- weight transpose + bf16 convert: W[K][N] f32 -> WT[N][K] bf16 ----
__global__ __launch_bounds__(256) void wtrans_kernel(
    const float* __restrict__ W, unsigned short* __restrict__ WT, int K, int N) {
  __shared__ float t[64][65];
  const int n0 = blockIdx.x * 64, k0 = blockIdx.y * 64;
  const int tid = threadIdx.x;
  const int kr = tid >> 4, ns = (tid & 15) * 4;
#pragma unroll
  for (int i = 0; i < 4; ++i) {
    const int k = kr + i * 16;
    const float4 v = *(const float4*)&W[(size_t)(k0 + k) * N + n0 + ns];
    t[k][ns + 0] = v.x; t[k][ns + 1] = v.y; t[k][ns + 2] = v.z; t[k][ns + 3] = v.w;
  }
  __syncthreads();
  const int n = tid >> 2, ks = (tid & 3) * 16;
#pragma unroll
  for (int c = 0; c < 4; ++c) {
    ushort4 o;
    o.x = f2bf(t[ks + c * 4 + 0][n]);
    o.y = f2bf(t[ks + c * 4 + 1][n]);
    o.z = f2bf(t[ks + c * 4 + 2][n]);
    o.w = f2bf(t[ks + c * 4 + 3][n]);
    *(ushort4*)&WT[(size_t)(n0 + n) * K + k0 + ks + c * 4] = o;
  }
}

// ---------- m97-structure GEMM: C[M,N] = A[M,K] @ BT[N,K]^T (Q/out GEMMs) ----
template <bool A_KV, bool C_BF16>
__global__ __launch_bounds__(256) void gemm128_kernel(
    const unsigned short* __restrict__ A, const unsigned short* __restrict__ xn,
    const unsigned short* __restrict__ lnb, const unsigned short* __restrict__ BT,
    unsigned short* __restrict__ Cb, float* __restrict__ Cf,
    int M, int N, int K) {
  __shared__ __attribute__((aligned(16))) unsigned short As[128 * 32];
  __shared__ __attribute__((aligned(16))) unsigned short Bs[128 * 32];
  const int tid = threadIdx.x;
  const int col0 = blockIdx.x * 128, row0 = blockIdx.y * 128;
  const int srow = tid >> 2, skseg = (tid & 3) * 8;

  auto arow_ptr = [&](int grow) -> const unsigned short* {
    if (grow >= M) grow = M - 1;
    if (A_KV) {
      const int bt = grow / CNK, j = grow - bt * CNK;
      return (j < CN1) ? xn + ((size_t)(bt * CN1 + j)) * K + skseg
                       : lnb + ((size_t)(bt * CN2)) * K + skseg;  // ln[:, :, 0]
    }
    return A + (size_t)grow * K + skseg;
  };
  const unsigned short* a0 = arow_ptr(row0 + srow);
  const unsigned short* a1 = arow_ptr(row0 + 64 + srow);
  const unsigned short* b0 = BT + (size_t)(col0 + srow) * K + skseg;
  const unsigned short* b1 = BT + (size_t)(col0 + 64 + srow) * K + skseg;

  const int lane = tid & 63, wave = tid >> 6;
  const int wrow = (wave >> 1) * 64, wcol = (wave & 1) * 64;
  const int i16 = lane & 15, quad = lane >> 4;

  floatx4 acc[4][4] = {};
  for (int kt = 0; kt < K; kt += 32) {
    __syncthreads();
#if HAS_GLDS
    glds16(a0 + kt, &As[tid * 8]);
    glds16(a1 + kt, &As[2048 + tid * 8]);
    glds16(b0 + kt, &Bs[tid * 8]);
    glds16(b1 + kt, &Bs[2048 + tid * 8]);
#else
    *(uint4*)&As[tid * 8]        = *(const uint4*)(a0 + kt);
    *(uint4*)&As[2048 + tid * 8] = *(const uint4*)(a1 + kt);
    *(uint4*)&Bs[tid * 8]        = *(const uint4*)(b0 + kt);
    *(uint4*)&Bs[2048 + tid * 8] = *(const uint4*)(b1 + kt);
#endif
    __syncthreads();
    short8 af[4], bf[4];
#pragma unroll
    for (int ti = 0; ti < 4; ++ti)
      af[ti] = *(const short8*)&As[(wrow + ti * 16 + i16) * 32 + quad * 8];
#pragma unroll
    for (int tj = 0; tj < 4; ++tj)
      bf[tj] = *(const short8*)&Bs[(wcol + tj * 16 + i16) * 32 + quad * 8];
#pragma unroll
    for (int ti = 0; ti < 4; ++ti)
#pragma unroll
      for (int tj = 0; tj < 4; ++tj)
        acc[ti][tj] = mfma_bf16(af[ti], bf[tj], acc[ti][tj]);
  }
#pragma unroll
  for (int ti = 0; ti < 4; ++ti)
#pragma unroll
    for (int tj = 0; tj < 4; ++tj) {
      const int gc = col0 + wcol + tj * 16 + i16;
#pragma unroll
      for (int r = 0; r < 4; ++r) {
        const int gr = row0 + wrow + ti * 16 + quad * 4 + r;
        if (gr < M) {
          if (C_BF16) Cb[(size_t)gr * N + gc] = f2bf(acc[ti][tj][r]);
          else        Cf[(size_t)gr * N + gc] = acc[ti][tj][r];
        }
      }
    }
}

// ---------- KV GEMM: r3's proven 128^2/4-wave/3-slot-ring kernel -----------
// (best measured: 190 us total; 8-phase port measured 211-214 twice -> reverted)
// Split into TWO M-half launches via mb0 so the rocprof top-5 exposes the
// next-slowest kernels (otherwise 5 iterations of the single slowest kernel
// fill the whole view). Cost: B (4 MB) read once more; A traffic unchanged.
// Per phase (slice s of K=32): vmcnt(4) BEFORE barrier; read 4 B + 4 A frags;
// stage slice s+2 (4 glds); 16 MFMA. 3 blocks/CU (48 KiB LDS). Tail 4/0.
// Swizzle: read k-slot16 = quad ^ ((row>>1)&3); inverse applied to the
// GLOBAL source address (LDS dest lane-linear for global_load_lds).
template <bool A_KV>
__global__ __launch_bounds__(256) void gemmkv_kernel(
    const unsigned short* __restrict__ xn, const unsigned short* __restrict__ lnb,
    const unsigned short* __restrict__ BT, unsigned short* __restrict__ Cb,
    int M, int N, int K, int nbN, int mb0) {
  __shared__ __attribute__((aligned(16))) unsigned short As[3 * 4096];
  __shared__ __attribute__((aligned(16))) unsigned short Bs[3 * 4096];
  const int tid = threadIdx.x;

  // bijective XCD swizzle (grid % 8 == 0 by construction)
  const int raw = blockIdx.x;
  const int cpx = gridDim.x >> 3;
  const int virt = (raw & 7) * cpx + (raw >> 3);
  const int mb = virt / nbN, nb = virt - mb * nbN;
  const int row0 = (mb0 + mb) * 128, col0 = nb * 128;

  auto arow = [&](int grow) -> const unsigned short* {
    if (grow >= M) grow = M - 1;
    if (A_KV) {
      const int bt = grow / CNK, j = grow - bt * CNK;
      return (j < CN1) ? xn + ((size_t)(bt * CN1 + j)) * K
                       : lnb + ((size_t)(bt * CN2)) * K;   // ln[:, :, 0]
    }
    return (const unsigned short*)nullptr;  // unused
  };
  // staging chunks: slice = 128 rows x 32 shorts (8 KB per operand);
  // 512 chunks of 16B; thread t handles chunks t and t+256 of each operand.
  const int c0 = tid, c1 = tid + 256;
  const int rA0 = c0 >> 2, sA0 = (c0 & 3) ^ ((rA0 >> 1) & 3);
  const int rA1 = c1 >> 2, sA1 = (c1 & 3) ^ ((rA1 >> 1) & 3);
  const unsigned short* pA0 = arow(row0 + rA0) + sA0 * 8;
  const unsigned short* pA1 = arow(row0 + rA1) + sA1 * 8;
  const unsigned short* pB0 = BT + (size_t)(col0 + rA0) * K + sA0 * 8;
  const unsigned short* pB1 = BT + (size_t)(col0 + rA1) * K + sA1 * 8;

  auto stage = [&](int s) {
    const int sb = (s % 3) * 4096;
#if HAS_GLDS
    glds16(pA0 + s * 32, &As[sb + tid * 8]);
    glds16(pA1 + s * 32, &As[sb + 2048 + tid * 8]);
    glds16(pB0 + s * 32, &Bs[sb + tid * 8]);
    glds16(pB1 + s * 32, &Bs[sb + 2048 + tid * 8]);
#else
    *(uint4*)&As[sb + tid * 8]        = *(const uint4*)(pA0 + s * 32);
    *(uint4*)&As[sb + 2048 + tid * 8] = *(const uint4*)(pA1 + s * 32);
    *(uint4*)&Bs[sb + tid * 8]        = *(const uint4*)(pB0 + s * 32);
    *(uint4*)&Bs[sb + 2048 + tid * 8] = *(const uint4*)(pB1 + s * 32);
#endif
  };

  // fragment read offsets (swizzled), constant per thread
  const int lane = tid & 63, wave = tid >> 6;
  const int wr = wave >> 1, wc = wave & 1;     // 2M x 2N, 64x64 per wave
  const int i16 = lane & 15, quad = lane >> 4;
  int offA[4], offB[4];
#pragma unroll
  for (int ti = 0; ti < 4; ++ti) {
    const int r = wr * 64 + ti * 16 + i16;
    offA[ti] = r * 32 + (quad ^ ((r >> 1) & 3)) * 8;
  }
#pragma unroll
  for (int tj = 0; tj < 4; ++tj) {
    const int r = wc * 64 + tj * 16 + i16;
    offB[tj] = r * 32 + (quad ^ ((r >> 1) & 3)) * 8;
  }

  floatx4 acc[4][4] = {};
  const int NSL = K >> 5;           // slices of K=32 (NSL=32 here)
  stage(0); stage(1);               // lag-2 prologue (8 loads/thread)

  auto phase = [&](int s, bool do_stage) {
    const unsigned short* Asl = &As[(s % 3) * 4096];
    const unsigned short* Bsl = &Bs[(s % 3) * 4096];
    short8 bf[4], af[4];
#pragma unroll
    for (int tj = 0; tj < 4; ++tj) bf[tj] = *(const short8*)(Bsl + offB[tj]);
#pragma unroll
    for (int ti = 0; ti < 4; ++ti) af[ti] = *(const short8*)(Asl + offA[ti]);
    if (do_stage) stage(s + 2);
    __builtin_amdgcn_s_setprio(1);
#pragma unroll
    for (int ti = 0; ti < 4; ++ti)
#pragma unroll
      for (int tj = 0; tj < 4; ++tj)
        acc[ti][tj] = mfma_bf16(af[ti], bf[tj], acc[ti][tj]);
    __builtin_amdgcn_s_setprio(0);
  };

  for (int s = 0; s < NSL - 2; ++s) {
    FENCEV(4);
    SBAR;
    __builtin_amdgcn_sched_barrier(0);
    phase(s, true);
  }
  FENCEV(4);
  SBAR;
  __builtin_amdgcn_sched_barrier(0);
  phase(NSL - 2, false);
  FENCEV(0);
  SBAR;
  __builtin_amdgcn_sched_barrier(0);
  phase(NSL - 1, false);

#pragma unroll
  for (int ti = 0; ti < 4; ++ti)
#pragma unroll
    for (int tj = 0; tj < 4; ++tj) {
      const int gc = col0 + wc * 64 + tj * 16 + i16;
#pragma unroll
      for (int r = 0; r < 4; ++r) {
        const int gr = row0 + wr * 64 + ti * 16 + quad * 4 + r;
        if (gr < M) Cb[(size_t)gr * N + gc] = f2bf(acc[ti][tj][r]);
      }
    }
}

// ---------- dynamic head weights, stage 1: mean over latent rows ----------
__global__ __launch_bounds__(256) void dwmean_kernel(
    const float* __restrict__ lnf, float* __restrict__ meanp) {
  const int bt = blockIdx.x >> 2, dseg = blockIdx.x & 3;
  const int d = dseg * 256 + threadIdx.x;
  const float* base = lnf + (size_t)bt * CN2 * CD + d;
  float s = 0.f;
#pragma unroll 4
  for (int r = 0; r < CN2; ++r) s += base[(size_t)r * CD];
  meanp[bt * CD + d] = s * (1.0f / 64.0f);
}

// ---------- dw stage 2: hid = relu(mean @ Wd1 + bd1) ----------
__global__ __launch_bounds__(256) void dwmlp_kernel(
    const float* __restrict__ meanp, const float* __restrict__ Wd1,
    const float* __restrict__ bd1, float* __restrict__ hidp) {
  __shared__ float red[8][32];
  const int bt = blockIdx.x >> 3, og = blockIdx.x & 7;
  const int o = threadIdx.x & 31, seg = threadIdx.x >> 5;
  const int col = og * 32 + o;
  const float* mb = meanp + bt * CD;
  float s = 0.f;
#pragma unroll 4
  for (int d = seg * 128; d < seg * 128 + 128; ++d)
    s += mb[d] * Wd1[(size_t)d * 256 + col];
  red[seg][o] = s;
  __syncthreads();
  if (seg == 0) {
    float t = red[0][o];
#pragma unroll
    for (int k = 1; k < 8; ++k) t += red[k][o];
    hidp[bt * 256 + col] = fmaxf(t + bd1[col], 0.0f);
  }
}

// ---------- dw stage 3: dw = softmax(hid @ Wd2 + bd2) ----------
__global__ __launch_bounds__(256) void dwfin_kernel(
    const float* __restrict__ hidp, const float* __restrict__ Wd2,
    const float* __restrict__ bd2, float* __restrict__ dw) {
  __shared__ float red[16][16];
  __shared__ float lg[16];
  const int bt = blockIdx.x;
  const int h = threadIdx.x & 15, seg = threadIdx.x >> 4;
  const float* hb = hidp + bt * 256;
  float s = 0.f;
#pragma unroll
  for (int o = seg * 16; o < seg * 16 + 16; ++o)
    s += hb[o] * Wd2[o * 16 + h];
  red[seg][h] = s;
  __syncthreads();
  if (seg == 0) {
    float t = red[0][h];
#pragma unroll
    for (int k = 1; k < 16; ++k) t += red[k][h];
    lg[h] = t + bd2[h];
  }
  __syncthreads();
  if (threadIdx.x < 16) {
    float mx = lg[0];
#pragma unroll
    for (int k = 1; k < 16; ++k) mx = fmaxf(mx, lg[k]);
    float sum = 0.f;
#pragma unroll
    for (int k = 0; k < 16; ++k) sum += __expf(lg[k] - mx);
    dw[bt * 16 + threadIdx.x] = __expf(lg[threadIdx.x] - mx) / sum;
  }
}

// ---------- MFMA attention v2: block per (b,t,h), 4 waves x 16 q-rows ----------
__global__ __launch_bounds__(256) void attn_kernel(
    const unsigned short* __restrict__ Q,   // (BT*64) x 1024, col = h*64+d
    const unsigned short* __restrict__ KV,  // (BT*1025) x 2048, K then V
    const float* __restrict__ dw,           // BT x 16
    unsigned short* __restrict__ AO) {      // (BT*64) x 1024, col = h*64+d
  __shared__ __attribute__((aligned(16))) unsigned short ks[2][64 * 72];  // K: [key][d]
  __shared__ __attribute__((aligned(16))) unsigned short vt[2][64 * 72];  // V^T: [d][perm key]
  const int raw = blockIdx.x;
  const int bt = (raw & 7) * 4 + ((raw >> 3) >> 4);
  const int h  = (raw >> 3) & 15;
  const int tid = threadIdx.x;
  const int lane = tid & 63, wave = tid >> 6;
  const int i16 = lane & 15, quad = lane >> 4;
  const int wrow = wave * 16;

  const unsigned short* qbase =
      Q + ((size_t)(bt * 64 + wrow + i16)) * CINNER + h * 64;
  const short8 bq0 = *(const short8*)(qbase + quad * 8);        // d 0..31
  const short8 bq1 = *(const short8*)(qbase + 32 + quad * 8);   // d 32..63

  const int jrb = tid & 31, seg = tid >> 5;
  const int t_ = jrb & 15, hlf_ = jrb >> 4;
  const int vcol0 = ((t_ >> 2) << 3) + (t_ & 3) + 4 * hlf_;  // + c*32
  const unsigned short* kvb = KV + ((size_t)bt * CNK) * 2048 + h * 64 + seg * 8;

  uint4 kk[2], vv[2];
  auto load_tile = [&](int j0) {
#pragma unroll
    for (int c = 0; c < 2; ++c) {
      const int j = j0 + c * 32 + jrb;
      if (j < CNK) {
        const unsigned short* p = kvb + (size_t)j * 2048;
        kk[c] = *(const uint4*)p;
        vv[c] = *(const uint4*)(p + 1024);
      } else {
        kk[c] = make_uint4(0, 0, 0, 0);
        vv[c] = make_uint4(0, 0, 0, 0);
      }
    }
  };
  auto write_tile = [&](int buf) {
#pragma unroll
    for (int c = 0; c < 2; ++c) {
      const int jr = c * 32 + jrb;
      *(uint4*)&ks[buf][jr * 72 + seg * 8] = kk[c];
      const int vcol = c * 32 + vcol0;
      const unsigned int w[4] = {vv[c].x, vv[c].y, vv[c].z, vv[c].w};
#pragma unroll
      for (int p = 0; p < 4; ++p) {
        vt[buf][(seg * 8 + 2 * p + 0) * 72 + vcol] = (unsigned short)(w[p] & 0xffffu);
        vt[buf][(seg * 8 + 2 * p + 1) * 72 + vcol] = (unsigned short)(w[p] >> 16);
      }
    }
  };

  float l = 0.f;
  floatx4 O[4] = {{0,0,0,0}, {0,0,0,0}, {0,0,0,0}, {0,0,0,0}};
  const float expC = 0.18033688011112042f;  // 0.125 * log2(e)

  load_tile(0);
  write_tile(0);
  constexpr int NT = 17;  // ceil(1025/64)
  for (int t = 0; t < NT; ++t) {
    if (t + 1 < NT) load_tile((t + 1) * 64);
    __syncthreads();
    const int buf = t & 1;
    const unsigned short* ksb = ks[buf];
    const unsigned short* vtb = vt[buf];
#pragma unroll
    for (int c = 0; c < 2; ++c) {
      floatx4 s0 = {0,0,0,0}, s1 = {0,0,0,0};
      const short8 a00 = *(const short8*)&ksb[((2*c)   * 16 + i16) * 72 + quad * 8];
      const short8 a01 = *(const short8*)&ksb[((2*c)   * 16 + i16) * 72 + 32 + quad * 8];
      const short8 a10 = *(const short8*)&ksb[((2*c+1) * 16 + i16) * 72 + quad * 8];
      const short8 a11 = *(const short8*)&ksb[((2*c+1) * 16 + i16) * 72 + 32 + quad * 8];
      s0 = mfma_bf16(a00, bq0, s0); s0 = mfma_bf16(a01, bq1, s0);
      s1 = mfma_bf16(a10, bq0, s1); s1 = mfma_bf16(a11, bq1, s1);
      unsigned short pb0[4], pb1[4];
      if (t == NT - 1) {  // masked tail tile (keys 1024..1087; only 1024 valid)
#pragma unroll
        for (int r = 0; r < 4; ++r) {
          const int k0g = t * 64 + (2*c)   * 16 + quad * 4 + r;
          const int k1g = t * 64 + (2*c+1) * 16 + quad * 4 + r;
          const float p0 = (k0g < CNK) ? exp2f(s0[r] * expC) : 0.f;
          const float p1 = (k1g < CNK) ? exp2f(s1[r] * expC) : 0.f;
          l += p0 + p1;
          pb0[r] = f2bf(p0); pb1[r] = f2bf(p1);
        }
      } else {
#pragma unroll
        for (int r = 0; r < 4; ++r) {
          const float p0 = exp2f(s0[r] * expC);
          const float p1 = exp2f(s1[r] * expC);
          l += p0 + p1;
          pb0[r] = f2bf(p0); pb1[r] = f2bf(p1);
        }
      }
      const short8 bp = {
          (short)pb0[0], (short)pb0[1], (short)pb0[2], (short)pb0[3],
          (short)pb1[0], (short)pb1[1], (short)pb1[2], (short)pb1[3]};
#pragma unroll
      for (int dt = 0; dt < 4; ++dt) {
        const short8 av = *(const short8*)&vtb[(dt * 16 + i16) * 72 + c * 32 + quad * 8];
        O[dt] = mfma_bf16(av, bp, O[dt]);
      }
    }
    if (t + 1 < NT) write_tile((t + 1) & 1);
  }

  l += __shfl_xor(l, 16);
  l += __shfl_xor(l, 32);
  const float wsc = dw[bt * 16 + h] / l;
  unsigned short* obase = AO + ((size_t)(bt * 64 + wrow + i16)) * CINNER + h * 64;
#pragma unroll
  for (int dt = 0; dt < 4; ++dt)
#pragma unroll
    for (int r = 0; r < 4; ++r)
      obase[dt * 16 + quad * 4 + r] = f2bf(O[dt][r] * wsc);
}

// ---------- host ----------
extern "C" void kernel_launch(void* const* d_in, const int* in_sizes, int n_in,
                              void* d_out, int out_size, void* d_ws, size_t ws_size,
                              hipStream_t stream) {
  const float* x       = (const float*)d_in[0];
  const float* latents = (const float*)d_in[1];
  const float* gm  = (const float*)d_in[2];
  const float* bm  = (const float*)d_in[3];
  const float* gl  = (const float*)d_in[4];
  const float* bl  = (const float*)d_in[5];
  const float* Wq  = (const float*)d_in[6];
  const float* Wkv = (const float*)d_in[7];
  const float* Wout= (const float*)d_in[8];
  const float* Wd1 = (const float*)d_in[9];
  const float* bd1 = (const float*)d_in[10];
  const float* Wd2 = (const float*)d_in[11];
  const float* bd2 = (const float*)d_in[12];
  float* out = (float*)d_out;

  char* ws = (char*)d_ws;
  size_t off = 0;
  auto alloc = [&](size_t bytes) -> void* {
    void* p = ws + off;
    off += (bytes + 255) & ~(size_t)255;
    return p;
  };
  unsigned short* xn   = (unsigned short*)alloc((size_t)CBT * CN1 * CD * 2);      // 64 MB
  unsigned short* kv   = (unsigned short*)alloc((size_t)CBT * CNK * 2048 * 2);    // 131 MB
  float*          lnf  = (float*)        alloc((size_t)CBT * CN2 * CD * 4);       // 8 MB
  unsigned short* lnb  = (unsigned short*)alloc((size_t)CBT * CN2 * CD * 2);      // 4 MB
  unsigned short* wqT  = (unsigned short*)alloc((size_t)CD * CINNER * 2);         // 2 MB  [N][K]
  unsigned short* wkvT = (unsigned short*)alloc((size_t)CD * 2 * CINNER * 2);     // 4 MB  [2N][K]
  unsigned short* woT  = (unsigned short*)alloc((size_t)CINNER * CD * 2);         // 2 MB  [N][K]
  unsigned short* qb   = (unsigned short*)alloc((size_t)CBT * CN2 * CINNER * 2);  // 4 MB
  unsigned short* aob  = (unsigned short*)alloc((size_t)CBT * CN2 * CINNER * 2);  // 4 MB
  float*          dwp  = (float*)        alloc((size_t)CBT * CH * 4);
  float*          meanp= (float*)        alloc((size_t)CBT * CD * 4);             // 128 KB
  float*          hidp = (float*)        alloc((size_t)CBT * 256 * 4);            // 32 KB
  if (off > ws_size) return;  // signal: output stays zero (ws too small)

  // 1) layernorms (x -> bf16; latents -> bf16 + fp32)
  ln_kernel<<<CBT * CN1 / 4, 256, 0, stream>>>(x, gm, bm, xn, nullptr);
  ln_kernel<<<CBT * CN2 / 4, 256, 0, stream>>>(latents, gl, bl, lnb, lnf);
  // 2) weight transpose + bf16 convert: W[K][N] -> WT[N][K]
  wtrans_kernel<<<dim3(CINNER / 64, CD / 64), 256, 0, stream>>>(Wq, wqT, CD, CINNER);
  wtrans_kernel<<<dim3(2 * CINNER / 64, CD / 64), 256, 0, stream>>>(Wkv, wkvT, CD, 2 * CINNER);
  wtrans_kernel<<<dim3(CD / 64, CINNER / 64), 256, 0, stream>>>(Wout, woT, CINNER, CD);
  // 3) Q = ln @ Wq   (2048 x 1024 x 1024)
  gemm128_kernel<false, true><<<dim3(1024 / 128, 2048 / 128), 256, 0, stream>>>(
      lnb, nullptr, nullptr, wqT, qb, nullptr, 2048, 1024, 1024);
  // 4) KV = concat(xn, ln[:, :, 0:1]) @ Wkv   (32800 x 2048 x 1024)
  //    r3's proven 128^2/3-slot kernel, split into two M-half launches so
  //    the top-5 profile exposes the next-slowest dispatches.
  {
    const int MBtot = (CBT * CNK + 127) / 128;   // 257
    const int MB1 = 129, MB2 = MBtot - MB1;      // 129 + 128
    gemmkv_kernel<true><<<MB1 * 16, 256, 0, stream>>>(
        xn, lnb, wkvT, kv, CBT * CNK, 2048, 1024, 16, 0);
    gemmkv_kernel<true><<<MB2 * 16, 256, 0, stream>>>(
        xn, lnb, wkvT, kv, CBT * CNK, 2048, 1024, 16, MB1);
  }
  // 5) dynamic head weights (3-stage, parallel)
  dwmean_kernel<<<CBT * 4, 256, 0, stream>>>(lnf, meanp);
  dwmlp_kernel<<<CBT * 8, 256, 0, stream>>>(meanp, Wd1, bd1, hidp);
  dwfin_kernel<<<CBT, 256, 0, stream>>>(hidp, Wd2, bd2, dwp);
  // 6) attention (512 blocks = BT * H, XCD-grouped by bt)
  attn_kernel<<<CBT * CH, 256, 0, stream>>>(qb, kv, dwp, aob);
  // 7) out = AO @ Wout   (2048 x 1024 x 1024) -> fp32 d_out
  gemm128_kernel<false, false><<<dim3(1024 / 128, 2048 / 128), 256, 0, stream>>>(
      aob, nullptr, nullptr, woT, nullptr, out, 2048, 1024, 1024);
}